// Round 8
// baseline (378.266 us; speedup 1.0000x reference)
//
#include <hip/hip_runtime.h>
#include <hip/hip_bf16.h>
#include <cstdint>
#include <cstddef>

// ---------------------------------------------------------------------------
// CausalSelfAttention fused block, MI355X/gfx950.  Round 8:
//  - proj GEMM -> k_gemmQ<2> (256x128, full fill, 2-phase schedule)
//  - A/B dedup: store [xh|xl], [Wh|Wl]; remap k-offset at stage time
//  - attn: 2 q-heads per block (8 waves) share K/V staging; 16 waves/CU
// B=2 T=2048 D=2048 NH=16 NKV=4 HD=128 ROPE=64.
// ---------------------------------------------------------------------------

typedef __bf16 bf16_t;
typedef bf16_t bf16x8 __attribute__((ext_vector_type(8)));
typedef float f32x4 __attribute__((ext_vector_type(4)));

#define MFMA16(a, b, c) __builtin_amdgcn_mfma_f32_16x16x32_bf16((a), (b), (c), 0, 0, 0)
#define SBAR()   __builtin_amdgcn_s_barrier()
#define SCHED0() __builtin_amdgcn_sched_barrier(0)
#define LGKM0()  asm volatile("s_waitcnt lgkmcnt(0)" ::: "memory")

__device__ __forceinline__ bf16_t to_bf16(float f) {
  __hip_bfloat16 h = __float2bfloat16(f);
  return *reinterpret_cast<bf16_t*>(&h);
}

__device__ __forceinline__ void gload16(const bf16_t* g, bf16_t* l) {
  auto lds_ptr = reinterpret_cast<__attribute__((address_space(3))) unsigned int*>(
      reinterpret_cast<uintptr_t>(l));
  auto g_ptr = reinterpret_cast<const __attribute__((address_space(1))) unsigned int*>(
      reinterpret_cast<uintptr_t>(g));
  __builtin_amdgcn_global_load_lds(g_ptr, lds_ptr, 16, 0, 0);
}

// ---------------------------------------------------------------------------
// fp32 -> bf16 cast, vectorized
// ---------------------------------------------------------------------------
__global__ void k_cast_bf16(const float* __restrict__ in, bf16_t* __restrict__ o, long n) {
  long i = ((long)blockIdx.x * blockDim.x + threadIdx.x) * 4;
  const long step = (long)gridDim.x * blockDim.x * 4;
  for (; i < n; i += step) {
    const float4 v = *reinterpret_cast<const float4*>(in + i);
    bf16_t r[4] = {to_bf16(v.x), to_bf16(v.y), to_bf16(v.z), to_bf16(v.w)};
    *reinterpret_cast<uint64_t*>(o + i) = *reinterpret_cast<const uint64_t*>(r);
  }
}

// ---------------------------------------------------------------------------
// x split: in [4096][2048] fp32 -> x2 [4096][4096] bf16 = [xh | xl]
// ---------------------------------------------------------------------------
__global__ void k_split_x(const float* __restrict__ in, bf16_t* __restrict__ x2) {
  long i = ((long)blockIdx.x * blockDim.x + threadIdx.x) * 4;
  const long step = (long)gridDim.x * blockDim.x * 4;
  for (; i < (long)4096 * 2048; i += step) {
    const float4 v = *reinterpret_cast<const float4*>(in + i);
    const long row = i >> 11, col = i & 2047;
    bf16_t h[4], l[4];
    const float vv[4] = {v.x, v.y, v.z, v.w};
#pragma unroll
    for (int j = 0; j < 4; ++j) {
      h[j] = to_bf16(vv[j]);
      l[j] = to_bf16(vv[j] - (float)h[j]);
    }
    bf16_t* rp = x2 + row * 4096;
    *reinterpret_cast<uint64_t*>(rp + col) = *reinterpret_cast<const uint64_t*>(h);
    *reinterpret_cast<uint64_t*>(rp + 2048 + col) = *reinterpret_cast<const uint64_t*>(l);
  }
}

// ---------------------------------------------------------------------------
// W split: W [R][2048] fp32 -> w2 [R][4096] = [Wh | Wl]
// ---------------------------------------------------------------------------
__global__ void k_split_w(const float* __restrict__ W, bf16_t* __restrict__ w2, long n) {
  long i = ((long)blockIdx.x * blockDim.x + threadIdx.x) * 4;
  const long step = (long)gridDim.x * blockDim.x * 4;
  for (; i < n; i += step) {
    const float4 v = *reinterpret_cast<const float4*>(W + i);
    const long row = i >> 11, col = i & 2047;
    bf16_t h[4], l[4];
    const float vv[4] = {v.x, v.y, v.z, v.w};
#pragma unroll
    for (int j = 0; j < 4; ++j) {
      h[j] = to_bf16(vv[j]);
      l[j] = to_bf16(vv[j] - (float)h[j]);
    }
    bf16_t* rp = w2 + row * 4096;
    *reinterpret_cast<uint64_t*>(rp + col) = *reinterpret_cast<const uint64_t*>(h);
    *reinterpret_cast<uint64_t*>(rp + 2048 + col) = *reinterpret_cast<const uint64_t*>(l);
  }
}

// ---------------------------------------------------------------------------
// RoPE cos/sin table: [T=2048][32]
// ---------------------------------------------------------------------------
__global__ void k_rope_tab(float* __restrict__ ctab, float* __restrict__ stab) {
  const int idx = blockIdx.x * blockDim.x + threadIdx.x;
  if (idx >= 2048 * 32) return;
  const int t = idx >> 5, i = idx & 31;
  const float freq = exp2f(-(float)i * 0.2076205059304601f);  // 10000^(-i/64)
  const float f = (float)t * freq;
  ctab[idx] = cosf(f);
  stab[idx] = sinf(f);
}

// ---------------------------------------------------------------------------
// 256 x (64*NBU) NT GEMM: C[m,n] = sum_k A'[m,k]*B'[n,k], fp32 out, where
// A'(k) reads A col (k>=4096 ? k-4096 : k)   ([xh|xl|xh] virtual from [xh|xl])
// B'(k) reads B col (k>=2048 ? k-2048 : k)   ([Wh|Wh|Wl] virtual from [Wh|Wl])
// (both remaps are no-ops when K<=2048, e.g. the projection GEMM).
// 512 threads = 8 waves (2M x 4N); BK=64; LDS = 2 bufs x (4+NBU) units of
// 64rows x 64cols, slot-XOR swizzle (slot ^= row&7), global_load_lds 16B.
// 2-phase: reads+MFMA(mh0) | lgkm0+SBAR | stage(t+2)+vmcnt(4+NBU)+
// MFMA(mh1, reg-only) | SBAR.  Requires M%256==0, N%(64*NBU)==0, K%64==0,
// nkt>=2, grid (N/(64*NBU), M/256), nwg%8==0.
// ---------------------------------------------------------------------------
template <int NBU>
__global__ __launch_bounds__(512, 2) void k_gemmQ(
    const bf16_t* __restrict__ A, const bf16_t* __restrict__ Bm,
    float* __restrict__ C, int M, int N, int K, int lda, int ldb)
{
  __shared__ __align__(16) bf16_t lds[2][(4 + NBU) * 4096];
  const int tid = threadIdx.x;
  const int l = tid & 63, w = tid >> 6;
  const int lrow = l & 15, lk = l >> 4;
  const int wm = w >> 2, wn = w & 3;

  const int nwg = gridDim.x * gridDim.y;
  int lin = blockIdx.y * gridDim.x + blockIdx.x;
  lin = (lin & 7) * (nwg >> 3) + (lin >> 3);
  const int m0 = (lin / gridDim.x) * 256, n0 = (lin % gridDim.x) * (64 * NBU);

  // staging: thread -> (unit-row tid>>3, phys slot tid&7); src col = (slot ^ row&7)*8
  const int srow = tid >> 3;
  const int scol = ((tid & 7) ^ (srow & 7)) << 3;
  const bf16_t* gP[4 + NBU];
#pragma unroll
  for (int u = 0; u < 4; ++u) gP[u] = A + (size_t)(m0 + u * 64 + srow) * lda + scol;
#pragma unroll
  for (int u = 0; u < NBU; ++u) gP[4 + u] = Bm + (size_t)(n0 + u * 64 + srow) * ldb + scol;

  auto stageAll = [&](int buf, int k0) {
    const int kA = (k0 >= 4096) ? k0 - 4096 : k0;   // [xh|xl|xh] virtual
    const int kB = (k0 >= 2048) ? k0 - 2048 : k0;   // [Wh|Wh|Wl] virtual
#pragma unroll
    for (int u = 0; u < 4 + NBU; ++u)
      gload16(gP[u] + (u < 4 ? kA : kB), &lds[buf][u * 4096 + tid * 8]);
  };
  auto rdA = [&](int buf, int mf, int ks) -> bf16x8 {
    const int row = wm * 128 + mf * 16 + lrow;            // 0..255
    const int slot = ((ks << 2) | lk) ^ (row & 7);
    return *reinterpret_cast<const bf16x8*>(&lds[buf][row * 64 + slot * 8]);
  };
  auto rdB = [&](int buf, int nf, int ks) -> bf16x8 {
    const int row = wn * (16 * NBU) + nf * 16 + lrow;     // 0..64*NBU-1
    const int slot = ((ks << 2) | lk) ^ (row & 7);
    return *reinterpret_cast<const bf16x8*>(&lds[buf][16384 + row * 64 + slot * 8]);
  };

  f32x4 acc[8][NBU] = {};
  const int nkt = K >> 6;

  stageAll(0, 0);
  stageAll(1, nkt > 1 ? 64 : 0);
  if constexpr (NBU == 3) { asm volatile("s_waitcnt vmcnt(7)" ::: "memory"); }
  else                    { asm volatile("s_waitcnt vmcnt(6)" ::: "memory"); }
  SCHED0();
  SBAR(); SCHED0();

  bf16x8 aA[8][2], bB[NBU][2];
  for (int kt = 0; kt < nkt; ++kt) {
    const int b = kt & 1;
    const int kn2 = (kt + 2 < nkt ? kt + 2 : nkt - 1) << 6;

    // phase 1: read all frags of tile t, MFMA upper half (mh0)
#pragma unroll
    for (int mf = 0; mf < 8; ++mf) { aA[mf][0] = rdA(b, mf, 0); aA[mf][1] = rdA(b, mf, 1); }
#pragma unroll
    for (int nf = 0; nf < NBU; ++nf) { bB[nf][0] = rdB(b, nf, 0); bB[nf][1] = rdB(b, nf, 1); }
    __builtin_amdgcn_s_setprio(1);
#pragma unroll
    for (int mf = 0; mf < 4; ++mf)
#pragma unroll
      for (int nf = 0; nf < NBU; ++nf)
#pragma unroll
        for (int ks = 0; ks < 2; ++ks)
          acc[mf][nf] = MFMA16(aA[mf][ks], bB[nf][ks], acc[mf][nf]);
    __builtin_amdgcn_s_setprio(0);
    LGKM0(); SCHED0();       // all my ds_reads of buf b complete
    SBAR(); SCHED0();        // ... on every wave -> safe to overwrite buf b

    // phase 2: stage tile t+2 over dead buf b; wait tile t+1; MFMA lower half
    stageAll(b, kn2);
    if constexpr (NBU == 3) { asm volatile("s_waitcnt vmcnt(7)" ::: "memory"); }
    else                    { asm volatile("s_waitcnt vmcnt(6)" ::: "memory"); }
    SCHED0();
    __builtin_amdgcn_s_setprio(1);
#pragma unroll
    for (int mf = 4; mf < 8; ++mf)
#pragma unroll
      for (int nf = 0; nf < NBU; ++nf)
#pragma unroll
        for (int ks = 0; ks < 2; ++ks)
          acc[mf][nf] = MFMA16(aA[mf][ks], bB[nf][ks], acc[mf][nf]);
    __builtin_amdgcn_s_setprio(0);
    SBAR(); SCHED0();        // all waves past vmcnt -> t+1 resident for next reads
  }

  // C-write
#pragma unroll
  for (int mf = 0; mf < 8; ++mf) {
    const int row = m0 + wm * 128 + mf * 16 + lk * 4;
#pragma unroll
    for (int nf = 0; nf < NBU; ++nf) {
      const int col = n0 + wn * (16 * NBU) + nf * 16 + lrow;
#pragma unroll
      for (int rg = 0; rg < 4; ++rg)
        C[(size_t)(row + rg) * N + col] = acc[mf][nf][rg];
    }
  }
  (void)M;
}

// ---------------------------------------------------------------------------
// QKV epilogue.  qkv raw = [4096][3072] f32 (q | k | v).  RMS-norm(q,k) +
// partial RoPE in fp32; q gets gain*(1/sqrt(128))*log2(e) folded in, stored
// hi/lo bf16 [.][256]; k plain bf16 [.][128]; v += ve_embed, plain bf16.
// ---------------------------------------------------------------------------
__global__ __launch_bounds__(256) void k_qkv_epi(
    const float* __restrict__ qkv, const float* __restrict__ ve,
    const float* __restrict__ qgain,
    const float* __restrict__ ctab, const float* __restrict__ stab,
    bf16_t* __restrict__ qn2, bf16_t* __restrict__ kn, bf16_t* __restrict__ vn)
{
  const int blk = blockIdx.x;           // b*2048 + t
  const int b = blk >> 11, t = blk & 2047;
  const int w = threadIdx.x >> 6, l = threadIdx.x & 63;
  const int i32 = l & 31;
  const float c = ctab[t * 32 + i32], s = stab[t * 32 + i32];
  const float EPS = 1.1920929e-07f;
  constexpr float SCALE_L2E = 0.088388347648318447f * 1.4426950408889634f;

  // Q: wave w handles heads w, w+4, w+8, w+12
#pragma unroll
  for (int it = 0; it < 4; ++it) {
    const int h = w + it * 4;
    const float* row = qkv + (size_t)blk * 3072 + h * 128;
    float x0 = row[l], x1 = row[l + 64];
    float ss = x0 * x0 + x1 * x1;
#pragma unroll
    for (int off = 32; off; off >>= 1) ss += __shfl_xor(ss, off);
    const float rn = rsqrtf(ss * (1.0f / 128.0f) + EPS);
    x0 *= rn; x1 *= rn;
    const float p = __shfl_xor(x0, 32);
    float xr = (l < 32) ? (x0 * c - p * s) : (p * s + x0 * c);
    const float g = qgain[h] * SCALE_L2E;
    xr *= g; x1 *= g;
    bf16_t* orow = qn2 + (((size_t)(b * 16 + h)) * 2048 + t) * 256;
    const bf16_t h0 = to_bf16(xr), h1 = to_bf16(x1);
    orow[l] = h0;        orow[128 + l] = to_bf16(xr - (float)h0);
    orow[l + 64] = h1;   orow[192 + l] = to_bf16(x1 - (float)h1);
  }
  // K: wave w -> kv head w (plain bf16)
  {
    const float* row = qkv + (size_t)blk * 3072 + 2048 + w * 128;
    float x0 = row[l], x1 = row[l + 64];
    float ss = x0 * x0 + x1 * x1;
#pragma unroll
    for (int off = 32; off; off >>= 1) ss += __shfl_xor(ss, off);
    const float rn = rsqrtf(ss * (1.0f / 128.0f) + EPS);
    x0 *= rn; x1 *= rn;
    const float p = __shfl_xor(x0, 32);
    const float xr = (l < 32) ? (x0 * c - p * s) : (p * s + x0 * c);
    bf16_t* orow = kn + (((size_t)(b * 4 + w)) * 2048 + t) * 128;
    orow[l] = to_bf16(xr);
    orow[l + 64] = to_bf16(x1);
  }
  // V: wave w -> kv head w ; v = vraw + ve
  {
    const float* row = qkv + (size_t)blk * 3072 + 2560 + w * 128;
    const float* verow = ve + (size_t)blk * 512 + w * 128;
    bf16_t* orow = vn + (((size_t)(b * 4 + w)) * 2048 + t) * 128;
    orow[l] = to_bf16(row[l] + verow[l]);
    orow[l + 64] = to_bf16(row[l + 64] + verow[l + 64]);
  }
}

// ---------------------------------------------------------------------------
// Causal GQA flash attention.  2 q-heads per block (same kv head), 8 waves:
// waves 0-3 -> head h0 strips, waves 4-7 -> head h0+1.  QBLK=64 rows/head,
// KVBLK=64, longest-qt-first.  q hi/lo (2-term S), k plain.
// LDS: lsK [64][136] padded, lsV^T [128][72] XOR-swizzled, lsP per-wave
// [16][72].  54.3KB -> 2 blocks/CU (16 waves).  K/V staged once per block,
// shared by both heads; K+V reg-prefetched one tile ahead.
// ---------------------------------------------------------------------------
__global__ __launch_bounds__(512, 4) void k_attn(
    const bf16_t* __restrict__ qn2, const bf16_t* __restrict__ kn,
    const bf16_t* __restrict__ vn, bf16_t* __restrict__ y)
{
  __shared__ __align__(16) bf16_t lsK[64 * 136];      // 17408 B
  __shared__ __align__(16) bf16_t lsV[128 * 72];      // 18432 B
  __shared__ __align__(16) bf16_t lsPb[8][16 * 72];   // 18432 B
  const int qt = 31 - (int)blockIdx.y;  // longest first
  const int hp = blockIdx.x;            // 0..15
  const int b = hp >> 3, e = hp & 7;
  const int kvh = e >> 1;
  const int tid = threadIdx.x, w = tid >> 6, l = tid & 63;
  const int lrow = l & 15, lk = l >> 4;
  const int head = e * 2 + (w >> 2);     // waves 0-3: h0, waves 4-7: h0+1
  const int ws = w & 3;                  // strip within the head's 64-row tile
  const int qbase = qt * 64 + ws * 16;
  constexpr float NEG = -1e30f;
  bf16_t* lsP = lsPb[w];

  // Q fragments (A-frag: row = lane&15, k = lk*8+j), hi and lo
  const bf16_t* qp = qn2 + ((size_t)(b * 16 + head) * 2048) * 256;
  bf16x8 aQh[4], aQl[4];
#pragma unroll
  for (int kf = 0; kf < 4; ++kf) {
    const size_t base = (size_t)(qbase + lrow) * 256 + kf * 32 + lk * 8;
    aQh[kf] = *reinterpret_cast<const bf16x8*>(qp + base);
    aQl[kf] = *reinterpret_cast<const bf16x8*>(qp + base + 128);
  }

  const bf16_t* kp = kn + ((size_t)(b * 4 + kvh) * 2048) * 128;
  const bf16_t* vp = vn + ((size_t)(b * 4 + kvh) * 2048) * 128;

  f32x4 o[8] = {};
  float mst[4], lst[4];
#pragma unroll
  for (int rg = 0; rg < 4; ++rg) { mst[rg] = NEG; lst[rg] = 0.f; }

  // K/V register prefetch: chunk cch = tid + it*512; row = cch>>4, slot = cch&15
  bf16x8 kreg[2], vreg[2];
  auto loadKV = [&](int t0) {
#pragma unroll
    for (int it = 0; it < 2; ++it) {
      const int cch = tid + it * 512;
      const size_t goff = (size_t)(t0 + (cch >> 4)) * 128 + (cch & 15) * 8;
      kreg[it] = *reinterpret_cast<const bf16x8*>(kp + goff);
      vreg[it] = *reinterpret_cast<const bf16x8*>(vp + goff);
    }
  };
  loadKV(0);

  const int ntiles = qt + 1;
  for (int tt = 0; tt < ntiles; ++tt) {
    __syncthreads();  // prior tile's K/V LDS reads done before restage
    // stage K [64][136] + V^T [128][72] (col' = kv ^ ((dg&7)<<3)) from regs
#pragma unroll
    for (int it = 0; it < 2; ++it) {
      const int cch = tid + it * 512;
      const int r = cch >> 4, dg = cch & 15;
      *reinterpret_cast<bf16x8*>(&lsK[r * 136 + dg * 8]) = kreg[it];
      const int colb = r ^ ((dg & 7) << 3);
#pragma unroll
      for (int j = 0; j < 8; ++j) lsV[(dg * 8 + j) * 72 + colb] = vreg[it][j];
    }
    if (tt + 1 < ntiles) loadKV((tt + 1) * 64);
    __syncthreads();  // staged data visible

    // S = Qh*Kh + Ql*Kh  (16 q-rows x 64 kv)
    f32x4 sacc[4] = {};
#pragma unroll
    for (int cf = 0; cf < 4; ++cf) {
      const int krow = cf * 16 + lrow;
#pragma unroll
      for (int kf = 0; kf < 4; ++kf) {
        const bf16x8 bK = *reinterpret_cast<const bf16x8*>(
            &lsK[krow * 136 + kf * 32 + lk * 8]);
        sacc[cf] = MFMA16(aQh[kf], bK, sacc[cf]);
        sacc[cf] = MFMA16(aQl[kf], bK, sacc[cf]);
      }
    }

    // online softmax, log2 domain; mask only on diagonal tile
    if (tt == qt) {
#pragma unroll
      for (int rg = 0; rg < 4; ++rg) {
        const int qi = ws * 16 + lk * 4 + rg;  // within-tile row
#pragma unroll
        for (int cf = 0; cf < 4; ++cf)
          if (cf * 16 + lrow > qi) sacc[cf][rg] = NEG;
      }
    }
    float pmax[4];
#pragma unroll
    for (int rg = 0; rg < 4; ++rg) {
      float mx = fmaxf(fmaxf(sacc[0][rg], sacc[1][rg]),
                       fmaxf(sacc[2][rg], sacc[3][rg]));
      mx = fmaxf(mx, __shfl_xor(mx, 1));
      mx = fmaxf(mx, __shfl_xor(mx, 2));
      mx = fmaxf(mx, __shfl_xor(mx, 4));
      mx = fmaxf(mx, __shfl_xor(mx, 8));
      pmax[rg] = mx;
    }
    const bool grow = (pmax[0] > mst[0] + 8.f) | (pmax[1] > mst[1] + 8.f) |
                      (pmax[2] > mst[2] + 8.f) | (pmax[3] > mst[3] + 8.f);
    if (__any(grow)) {
#pragma unroll
      for (int rg = 0; rg < 4; ++rg) {
        const float mnew = fmaxf(mst[rg], pmax[rg]);
        const float alpha = exp2f(mst[rg] - mnew);
        mst[rg] = mnew;
        lst[rg] *= alpha;
#pragma unroll
        for (int df = 0; df < 8; ++df) o[df][rg] *= alpha;
      }
    }
#pragma unroll
    for (int rg = 0; rg < 4; ++rg) {
      float rsum = 0.f;
#pragma unroll
      for (int cf = 0; cf < 4; ++cf) {
        const float p = exp2f(sacc[cf][rg] - mst[rg]);
        sacc[cf][rg] = p;
        rsum += p;
      }
      rsum += __shfl_xor(rsum, 1);
      rsum += __shfl_xor(rsum, 2);
      rsum += __shfl_xor(rsum, 4);
      rsum += __shfl_xor(rsum, 8);
      lst[rg] += rsum;
    }

    // P -> per-wave LDS (A-frag layout [16][72]); same-wave write->read
#pragma unroll
    for (int cf = 0; cf < 4; ++cf)
#pragma unroll
      for (int rg = 0; rg < 4; ++rg)
        lsP[(lk * 4 + rg) * 72 + cf * 16 + lrow] = to_bf16(sacc[cf][rg]);
    // PV
#pragma unroll
    for (int k2 = 0; k2 < 2; ++k2) {
      const bf16x8 aP = *reinterpret_cast<const bf16x8*>(
          &lsP[lrow * 72 + k2 * 32 + lk * 8]);
#pragma unroll
      for (int df = 0; df < 8; ++df) {
        const int row = df * 16 + lrow;
        const int colb = (k2 * 32 + lk * 8) ^ (((row >> 3) & 7) << 3);
        const bf16x8 bV = *reinterpret_cast<const bf16x8*>(&lsV[row * 72 + colb]);
        o[df] = MFMA16(aP, bV, o[df]);
      }
    }
  }

  // normalize + write y [b][t][head*128+d]
#pragma unroll
  for (int rg = 0; rg < 4; ++rg) {
    const float inv = 1.0f / lst[rg];
    const int qi = qbase + lk * 4 + rg;
    const size_t rowoff = ((size_t)(b * 2048 + qi)) * 2048 + head * 128;
#pragma unroll
    for (int df = 0; df < 8; ++df)
      y[rowoff + df * 16 + lrow] = to_bf16(o[df][rg] * inv);
  }
}

// ---------------------------------------------------------------------------
extern "C" void kernel_launch(void* const* d_in, const int* in_sizes, int n_in,
                              void* d_out, int out_size, void* d_ws, size_t ws_size,
                              hipStream_t stream) {
  const float* x  = (const float*)d_in[0];
  const float* ve = (const float*)d_in[1];
  const float* Wq = (const float*)d_in[2];
  const float* Wk = (const float*)d_in[3];
  const float* Wv = (const float*)d_in[4];
  const float* Wp = (const float*)d_in[5];
  const float* qg = (const float*)d_in[6];
  float* out = (float*)d_out;

  char* ws = (char*)d_ws;
  size_t off = 0;
  auto alloc = [&](size_t bytes) -> char* {
    char* p = ws + off;
    off += (bytes + 255) & ~(size_t)255;
    return p;
  };

  bf16_t* x2     = (bf16_t*)alloc((size_t)4096 * 4096 * 2);  // [xh|xl]; later qn2
  bf16_t* wqkv2  = (bf16_t*)alloc((size_t)3072 * 4096 * 2);  // rows Wq|Wk|Wv, [Wh|Wl]
  bf16_t* wpb    = (bf16_t*)alloc((size_t)2048 * 2048 * 2);
  float*  qkvraw = (float*)alloc((size_t)4096 * 3072 * 4);   // later yb
  bf16_t* kn     = (bf16_t*)alloc((size_t)2 * 4 * 2048 * 128 * 2);
  bf16_t* vn     = (bf16_t*)alloc((size_t)2 * 4 * 2048 * 128 * 2);
  float*  ctab   = (float*)alloc((size_t)2048 * 32 * 4);
  float*  stab   = (float*)alloc((size_t)2048 * 32 * 4);
  bf16_t* qn2    = x2;               // x2 dead after QKV GEMM (32MB = 32MB)
  bf16_t* yb     = (bf16_t*)qkvraw;  // qkvraw dead after epilogue
  (void)ws_size; (void)in_sizes; (void)n_in; (void)out_size;

  k_split_x<<<2048, 256, 0, stream>>>(x, x2);
  k_split_w<<<1024, 256, 0, stream>>>(Wq, wqkv2, (long)2048 * 2048);
  k_split_w<<<512,  256, 0, stream>>>(Wk, wqkv2 + (size_t)2048 * 4096, (long)512 * 2048);
  k_split_w<<<512,  256, 0, stream>>>(Wv, wqkv2 + (size_t)2560 * 4096, (long)512 * 2048);
  k_cast_bf16<<<1024, 256, 0, stream>>>(Wp, wpb, (long)2048 * 2048);
  k_rope_tab<<<256, 256, 0, stream>>>(ctab, stab);

  // qkvraw = [xh|xl|xh]·[Wh|Wh|Wl]^T  (M=4096 N=3072 K=6144 virtual; 256x192)
  k_gemmQ<3><<<dim3(16, 16), 512, 0, stream>>>(x2, wqkv2, qkvraw, 4096, 3072, 6144, 4096, 4096);

  k_qkv_epi<<<4096, 256, 0, stream>>>(qkvraw, ve, qg, ctab, stab, qn2, kn, vn);

  k_attn<<<dim3(16, 32), 512, 0, stream>>>(qn2, kn, vn, yb);

  // out = y · Wp^T  (M=4096 N=2048 K=2048; 256x128)
  k_gemmQ<2><<<dim3(16, 16), 512, 0, stream>>>(yb, wpb, out, 4096, 2048, 2048, 2048, 2048);
}

// Round 9
// 325.963 us; speedup vs baseline: 1.1605x; 1.1605x over previous
//
#include <hip/hip_runtime.h>
#include <hip/hip_bf16.h>
#include <cstdint>
#include <cstddef>

// ---------------------------------------------------------------------------
// CausalSelfAttention fused block, MI355X/gfx950.  Round 9:
//  - attn: revert to R5 kernel exactly (256 thr, lb(256,3), VGPR~84; R8's
//    lb(512,4) capped VGPR at 64 -> spills -> 183us regression)
//  - keep R8 GEMMs: k_gemmQ<3> QKV w/ k-remap dedup, k_gemmQ<2> proj
// B=2 T=2048 D=2048 NH=16 NKV=4 HD=128 ROPE=64.
// ---------------------------------------------------------------------------

typedef __bf16 bf16_t;
typedef bf16_t bf16x8 __attribute__((ext_vector_type(8)));
typedef float f32x4 __attribute__((ext_vector_type(4)));

#define MFMA16(a, b, c) __builtin_amdgcn_mfma_f32_16x16x32_bf16((a), (b), (c), 0, 0, 0)
#define SBAR()   __builtin_amdgcn_s_barrier()
#define SCHED0() __builtin_amdgcn_sched_barrier(0)
#define LGKM0()  asm volatile("s_waitcnt lgkmcnt(0)" ::: "memory")

__device__ __forceinline__ bf16_t to_bf16(float f) {
  __hip_bfloat16 h = __float2bfloat16(f);
  return *reinterpret_cast<bf16_t*>(&h);
}

__device__ __forceinline__ void gload16(const bf16_t* g, bf16_t* l) {
  auto lds_ptr = reinterpret_cast<__attribute__((address_space(3))) unsigned int*>(
      reinterpret_cast<uintptr_t>(l));
  auto g_ptr = reinterpret_cast<const __attribute__((address_space(1))) unsigned int*>(
      reinterpret_cast<uintptr_t>(g));
  __builtin_amdgcn_global_load_lds(g_ptr, lds_ptr, 16, 0, 0);
}

// ---------------------------------------------------------------------------
// fp32 -> bf16 cast, vectorized
// ---------------------------------------------------------------------------
__global__ void k_cast_bf16(const float* __restrict__ in, bf16_t* __restrict__ o, long n) {
  long i = ((long)blockIdx.x * blockDim.x + threadIdx.x) * 4;
  const long step = (long)gridDim.x * blockDim.x * 4;
  for (; i < n; i += step) {
    const float4 v = *reinterpret_cast<const float4*>(in + i);
    bf16_t r[4] = {to_bf16(v.x), to_bf16(v.y), to_bf16(v.z), to_bf16(v.w)};
    *reinterpret_cast<uint64_t*>(o + i) = *reinterpret_cast<const uint64_t*>(r);
  }
}

// ---------------------------------------------------------------------------
// x split: in [4096][2048] fp32 -> x2 [4096][4096] bf16 = [xh | xl]
// ---------------------------------------------------------------------------
__global__ void k_split_x(const float* __restrict__ in, bf16_t* __restrict__ x2) {
  long i = ((long)blockIdx.x * blockDim.x + threadIdx.x) * 4;
  const long step = (long)gridDim.x * blockDim.x * 4;
  for (; i < (long)4096 * 2048; i += step) {
    const float4 v = *reinterpret_cast<const float4*>(in + i);
    const long row = i >> 11, col = i & 2047;
    bf16_t h[4], l[4];
    const float vv[4] = {v.x, v.y, v.z, v.w};
#pragma unroll
    for (int j = 0; j < 4; ++j) {
      h[j] = to_bf16(vv[j]);
      l[j] = to_bf16(vv[j] - (float)h[j]);
    }
    bf16_t* rp = x2 + row * 4096;
    *reinterpret_cast<uint64_t*>(rp + col) = *reinterpret_cast<const uint64_t*>(h);
    *reinterpret_cast<uint64_t*>(rp + 2048 + col) = *reinterpret_cast<const uint64_t*>(l);
  }
}

// ---------------------------------------------------------------------------
// W split: W [R][2048] fp32 -> w2 [R][4096] = [Wh | Wl]
// ---------------------------------------------------------------------------
__global__ void k_split_w(const float* __restrict__ W, bf16_t* __restrict__ w2, long n) {
  long i = ((long)blockIdx.x * blockDim.x + threadIdx.x) * 4;
  const long step = (long)gridDim.x * blockDim.x * 4;
  for (; i < n; i += step) {
    const float4 v = *reinterpret_cast<const float4*>(W + i);
    const long row = i >> 11, col = i & 2047;
    bf16_t h[4], l[4];
    const float vv[4] = {v.x, v.y, v.z, v.w};
#pragma unroll
    for (int j = 0; j < 4; ++j) {
      h[j] = to_bf16(vv[j]);
      l[j] = to_bf16(vv[j] - (float)h[j]);
    }
    bf16_t* rp = w2 + row * 4096;
    *reinterpret_cast<uint64_t*>(rp + col) = *reinterpret_cast<const uint64_t*>(h);
    *reinterpret_cast<uint64_t*>(rp + 2048 + col) = *reinterpret_cast<const uint64_t*>(l);
  }
}

// ---------------------------------------------------------------------------
// RoPE cos/sin table: [T=2048][32]
// ---------------------------------------------------------------------------
__global__ void k_rope_tab(float* __restrict__ ctab, float* __restrict__ stab) {
  const int idx = blockIdx.x * blockDim.x + threadIdx.x;
  if (idx >= 2048 * 32) return;
  const int t = idx >> 5, i = idx & 31;
  const float freq = exp2f(-(float)i * 0.2076205059304601f);  // 10000^(-i/64)
  const float f = (float)t * freq;
  ctab[idx] = cosf(f);
  stab[idx] = sinf(f);
}

// ---------------------------------------------------------------------------
// 256 x (64*NBU) NT GEMM: C[m,n] = sum_k A'[m,k]*B'[n,k], fp32 out, where
// A'(k) reads A col (k>=4096 ? k-4096 : k)   ([xh|xl|xh] virtual from [xh|xl])
// B'(k) reads B col (k>=2048 ? k-2048 : k)   ([Wh|Wh|Wl] virtual from [Wh|Wl])
// (both remaps are no-ops when K<=2048, e.g. the projection GEMM).
// 512 threads = 8 waves (2M x 4N); BK=64; LDS = 2 bufs x (4+NBU) units of
// 64rows x 64cols, slot-XOR swizzle (slot ^= row&7), global_load_lds 16B.
// 2-phase: reads+MFMA(mh0) | lgkm0+SBAR | stage(t+2)+vmcnt(4+NBU)+
// MFMA(mh1, reg-only) | SBAR.  Requires M%256==0, N%(64*NBU)==0, K%64==0,
// nkt>=2, grid (N/(64*NBU), M/256), nwg%8==0.
// ---------------------------------------------------------------------------
template <int NBU>
__global__ __launch_bounds__(512, 2) void k_gemmQ(
    const bf16_t* __restrict__ A, const bf16_t* __restrict__ Bm,
    float* __restrict__ C, int M, int N, int K, int lda, int ldb)
{
  __shared__ __align__(16) bf16_t lds[2][(4 + NBU) * 4096];
  const int tid = threadIdx.x;
  const int l = tid & 63, w = tid >> 6;
  const int lrow = l & 15, lk = l >> 4;
  const int wm = w >> 2, wn = w & 3;

  const int nwg = gridDim.x * gridDim.y;
  int lin = blockIdx.y * gridDim.x + blockIdx.x;
  lin = (lin & 7) * (nwg >> 3) + (lin >> 3);
  const int m0 = (lin / gridDim.x) * 256, n0 = (lin % gridDim.x) * (64 * NBU);

  // staging: thread -> (unit-row tid>>3, phys slot tid&7); src col = (slot ^ row&7)*8
  const int srow = tid >> 3;
  const int scol = ((tid & 7) ^ (srow & 7)) << 3;
  const bf16_t* gP[4 + NBU];
#pragma unroll
  for (int u = 0; u < 4; ++u) gP[u] = A + (size_t)(m0 + u * 64 + srow) * lda + scol;
#pragma unroll
  for (int u = 0; u < NBU; ++u) gP[4 + u] = Bm + (size_t)(n0 + u * 64 + srow) * ldb + scol;

  auto stageAll = [&](int buf, int k0) {
    const int kA = (k0 >= 4096) ? k0 - 4096 : k0;   // [xh|xl|xh] virtual
    const int kB = (k0 >= 2048) ? k0 - 2048 : k0;   // [Wh|Wh|Wl] virtual
#pragma unroll
    for (int u = 0; u < 4 + NBU; ++u)
      gload16(gP[u] + (u < 4 ? kA : kB), &lds[buf][u * 4096 + tid * 8]);
  };
  auto rdA = [&](int buf, int mf, int ks) -> bf16x8 {
    const int row = wm * 128 + mf * 16 + lrow;            // 0..255
    const int slot = ((ks << 2) | lk) ^ (row & 7);
    return *reinterpret_cast<const bf16x8*>(&lds[buf][row * 64 + slot * 8]);
  };
  auto rdB = [&](int buf, int nf, int ks) -> bf16x8 {
    const int row = wn * (16 * NBU) + nf * 16 + lrow;     // 0..64*NBU-1
    const int slot = ((ks << 2) | lk) ^ (row & 7);
    return *reinterpret_cast<const bf16x8*>(&lds[buf][16384 + row * 64 + slot * 8]);
  };

  f32x4 acc[8][NBU] = {};
  const int nkt = K >> 6;

  stageAll(0, 0);
  stageAll(1, nkt > 1 ? 64 : 0);
  if constexpr (NBU == 3) { asm volatile("s_waitcnt vmcnt(7)" ::: "memory"); }
  else                    { asm volatile("s_waitcnt vmcnt(6)" ::: "memory"); }
  SCHED0();
  SBAR(); SCHED0();

  bf16x8 aA[8][2], bB[NBU][2];
  for (int kt = 0; kt < nkt; ++kt) {
    const int b = kt & 1;
    const int kn2 = (kt + 2 < nkt ? kt + 2 : nkt - 1) << 6;

    // phase 1: read all frags of tile t, MFMA upper half (mh0)
#pragma unroll
    for (int mf = 0; mf < 8; ++mf) { aA[mf][0] = rdA(b, mf, 0); aA[mf][1] = rdA(b, mf, 1); }
#pragma unroll
    for (int nf = 0; nf < NBU; ++nf) { bB[nf][0] = rdB(b, nf, 0); bB[nf][1] = rdB(b, nf, 1); }
    __builtin_amdgcn_s_setprio(1);
#pragma unroll
    for (int mf = 0; mf < 4; ++mf)
#pragma unroll
      for (int nf = 0; nf < NBU; ++nf)
#pragma unroll
        for (int ks = 0; ks < 2; ++ks)
          acc[mf][nf] = MFMA16(aA[mf][ks], bB[nf][ks], acc[mf][nf]);
    __builtin_amdgcn_s_setprio(0);
    LGKM0(); SCHED0();       // all my ds_reads of buf b complete
    SBAR(); SCHED0();        // ... on every wave -> safe to overwrite buf b

    // phase 2: stage tile t+2 over dead buf b; wait tile t+1; MFMA lower half
    stageAll(b, kn2);
    if constexpr (NBU == 3) { asm volatile("s_waitcnt vmcnt(7)" ::: "memory"); }
    else                    { asm volatile("s_waitcnt vmcnt(6)" ::: "memory"); }
    SCHED0();
    __builtin_amdgcn_s_setprio(1);
#pragma unroll
    for (int mf = 4; mf < 8; ++mf)
#pragma unroll
      for (int nf = 0; nf < NBU; ++nf)
#pragma unroll
        for (int ks = 0; ks < 2; ++ks)
          acc[mf][nf] = MFMA16(aA[mf][ks], bB[nf][ks], acc[mf][nf]);
    __builtin_amdgcn_s_setprio(0);
    SBAR(); SCHED0();        // all waves past vmcnt -> t+1 resident for next reads
  }

  // C-write
#pragma unroll
  for (int mf = 0; mf < 8; ++mf) {
    const int row = m0 + wm * 128 + mf * 16 + lk * 4;
#pragma unroll
    for (int nf = 0; nf < NBU; ++nf) {
      const int col = n0 + wn * (16 * NBU) + nf * 16 + lrow;
#pragma unroll
      for (int rg = 0; rg < 4; ++rg)
        C[(size_t)(row + rg) * N + col] = acc[mf][nf][rg];
    }
  }
  (void)M;
}

// ---------------------------------------------------------------------------
// QKV epilogue.  qkv raw = [4096][3072] f32 (q | k | v).  RMS-norm(q,k) +
// partial RoPE in fp32; q gets gain*(1/sqrt(128))*log2(e) folded in, stored
// hi/lo bf16 [.][256]; k plain bf16 [.][128]; v += ve_embed, plain bf16.
// ---------------------------------------------------------------------------
__global__ __launch_bounds__(256) void k_qkv_epi(
    const float* __restrict__ qkv, const float* __restrict__ ve,
    const float* __restrict__ qgain,
    const float* __restrict__ ctab, const float* __restrict__ stab,
    bf16_t* __restrict__ qn2, bf16_t* __restrict__ kn, bf16_t* __restrict__ vn)
{
  const int blk = blockIdx.x;           // b*2048 + t
  const int b = blk >> 11, t = blk & 2047;
  const int w = threadIdx.x >> 6, l = threadIdx.x & 63;
  const int i32 = l & 31;
  const float c = ctab[t * 32 + i32], s = stab[t * 32 + i32];
  const float EPS = 1.1920929e-07f;
  constexpr float SCALE_L2E = 0.088388347648318447f * 1.4426950408889634f;

  // Q: wave w handles heads w, w+4, w+8, w+12
#pragma unroll
  for (int it = 0; it < 4; ++it) {
    const int h = w + it * 4;
    const float* row = qkv + (size_t)blk * 3072 + h * 128;
    float x0 = row[l], x1 = row[l + 64];
    float ss = x0 * x0 + x1 * x1;
#pragma unroll
    for (int off = 32; off; off >>= 1) ss += __shfl_xor(ss, off);
    const float rn = rsqrtf(ss * (1.0f / 128.0f) + EPS);
    x0 *= rn; x1 *= rn;
    const float p = __shfl_xor(x0, 32);
    float xr = (l < 32) ? (x0 * c - p * s) : (p * s + x0 * c);
    const float g = qgain[h] * SCALE_L2E;
    xr *= g; x1 *= g;
    bf16_t* orow = qn2 + (((size_t)(b * 16 + h)) * 2048 + t) * 256;
    const bf16_t h0 = to_bf16(xr), h1 = to_bf16(x1);
    orow[l] = h0;        orow[128 + l] = to_bf16(xr - (float)h0);
    orow[l + 64] = h1;   orow[192 + l] = to_bf16(x1 - (float)h1);
  }
  // K: wave w -> kv head w (plain bf16)
  {
    const float* row = qkv + (size_t)blk * 3072 + 2048 + w * 128;
    float x0 = row[l], x1 = row[l + 64];
    float ss = x0 * x0 + x1 * x1;
#pragma unroll
    for (int off = 32; off; off >>= 1) ss += __shfl_xor(ss, off);
    const float rn = rsqrtf(ss * (1.0f / 128.0f) + EPS);
    x0 *= rn; x1 *= rn;
    const float p = __shfl_xor(x0, 32);
    const float xr = (l < 32) ? (x0 * c - p * s) : (p * s + x0 * c);
    bf16_t* orow = kn + (((size_t)(b * 4 + w)) * 2048 + t) * 128;
    orow[l] = to_bf16(xr);
    orow[l + 64] = to_bf16(x1);
  }
  // V: wave w -> kv head w ; v = vraw + ve
  {
    const float* row = qkv + (size_t)blk * 3072 + 2560 + w * 128;
    const float* verow = ve + (size_t)blk * 512 + w * 128;
    bf16_t* orow = vn + (((size_t)(b * 4 + w)) * 2048 + t) * 128;
    orow[l] = to_bf16(row[l] + verow[l]);
    orow[l + 64] = to_bf16(row[l + 64] + verow[l + 64]);
  }
}

// ---------------------------------------------------------------------------
// Causal GQA flash attention (R5 kernel, proven).  q hi/lo (2-term S), k
// plain.  QBLK=64 (4 waves x 16 q-rows), KVBLK=64, longest-qt-first.
// LDS: lsK [64][136] padded (2-way reads), lsV^T [128][72] XOR-swizzled,
// lsP per-wave [16][72].  45KB -> 3 blocks/CU.  2 barriers/tile.  K+V
// prefetched into registers one tile ahead.
// ---------------------------------------------------------------------------
__global__ __launch_bounds__(256, 3) void k_attn(
    const bf16_t* __restrict__ qn2, const bf16_t* __restrict__ kn,
    const bf16_t* __restrict__ vn, bf16_t* __restrict__ y)
{
  __shared__ __align__(16) bf16_t lsK[64 * 136];      // 17408 B
  __shared__ __align__(16) bf16_t lsV[128 * 72];      // 18432 B
  __shared__ __align__(16) bf16_t lsPb[4][16 * 72];   //  9216 B
  const int qt = 31 - (int)blockIdx.y;  // longest first
  const int bh = blockIdx.x;            // 0..31
  const int b = bh >> 4, h = bh & 15, kvh = h >> 2;
  const int tid = threadIdx.x, w = tid >> 6, l = tid & 63;
  const int lrow = l & 15, lk = l >> 4;
  const int qbase = qt * 64 + w * 16;
  constexpr float NEG = -1e30f;
  bf16_t* lsP = lsPb[w];

  // Q fragments (A-frag: row = lane&15, k = lk*8+j), hi and lo
  const bf16_t* qp = qn2 + ((size_t)(b * 16 + h) * 2048) * 256;
  bf16x8 aQh[4], aQl[4];
#pragma unroll
  for (int kf = 0; kf < 4; ++kf) {
    const size_t base = (size_t)(qbase + lrow) * 256 + kf * 32 + lk * 8;
    aQh[kf] = *reinterpret_cast<const bf16x8*>(qp + base);
    aQl[kf] = *reinterpret_cast<const bf16x8*>(qp + base + 128);
  }

  const bf16_t* kp = kn + ((size_t)(b * 4 + kvh) * 2048) * 128;
  const bf16_t* vp = vn + ((size_t)(b * 4 + kvh) * 2048) * 128;

  f32x4 o[8] = {};
  float mst[4], lst[4];
#pragma unroll
  for (int rg = 0; rg < 4; ++rg) { mst[rg] = NEG; lst[rg] = 0.f; }

  // K/V register prefetch (tile t0): chunk cch = tid + it*256,
  // row = cch>>4 (0..63), slot = cch&15.
  bf16x8 kreg[4], vreg[4];
  auto loadKV = [&](int t0) {
#pragma unroll
    for (int it = 0; it < 4; ++it) {
      const int cch = tid + it * 256;
      const size_t goff = (size_t)(t0 + (cch >> 4)) * 128 + (cch & 15) * 8;
      kreg[it] = *reinterpret_cast<const bf16x8*>(kp + goff);
      vreg[it] = *reinterpret_cast<const bf16x8*>(vp + goff);
    }
  };
  loadKV(0);

  const int ntiles = qt + 1;
  for (int tt = 0; tt < ntiles; ++tt) {
    __syncthreads();  // prior tile's K/V LDS reads done before restage
    // stage K [64][136] + V^T [128][72] (col' = kv ^ ((dg&7)<<3)) from regs
#pragma unroll
    for (int it = 0; it < 4; ++it) {
      const int cch = tid + it * 256;
      const int r = cch >> 4, dg = cch & 15;
      *reinterpret_cast<bf16x8*>(&lsK[r * 136 + dg * 8]) = kreg[it];
      const int colb = r ^ ((dg & 7) << 3);
#pragma unroll
      for (int j = 0; j < 8; ++j) lsV[(dg * 8 + j) * 72 + colb] = vreg[it][j];
    }
    // prefetch next tile's K/V (in flight across S + softmax + PV)
    if (tt + 1 < ntiles) loadKV((tt + 1) * 64);
    __syncthreads();  // staged data visible

    // S = Qh*Kh + Ql*Kh  (16 q-rows x 64 kv)
    f32x4 sacc[4] = {};
#pragma unroll
    for (int cf = 0; cf < 4; ++cf) {
      const int krow = cf * 16 + lrow;
#pragma unroll
      for (int kf = 0; kf < 4; ++kf) {
        const bf16x8 bK = *reinterpret_cast<const bf16x8*>(
            &lsK[krow * 136 + kf * 32 + lk * 8]);
        sacc[cf] = MFMA16(aQh[kf], bK, sacc[cf]);
        sacc[cf] = MFMA16(aQl[kf], bK, sacc[cf]);
      }
    }

    // online softmax, log2 domain; mask only on diagonal tile
    if (tt == qt) {
#pragma unroll
      for (int rg = 0; rg < 4; ++rg) {
        const int qi = w * 16 + lk * 4 + rg;  // within-tile row
#pragma unroll
        for (int cf = 0; cf < 4; ++cf)
          if (cf * 16 + lrow > qi) sacc[cf][rg] = NEG;
      }
    }
    float pmax[4];
#pragma unroll
    for (int rg = 0; rg < 4; ++rg) {
      float mx = fmaxf(fmaxf(sacc[0][rg], sacc[1][rg]),
                       fmaxf(sacc[2][rg], sacc[3][rg]));
      mx = fmaxf(mx, __shfl_xor(mx, 1));
      mx = fmaxf(mx, __shfl_xor(mx, 2));
      mx = fmaxf(mx, __shfl_xor(mx, 4));
      mx = fmaxf(mx, __shfl_xor(mx, 8));
      pmax[rg] = mx;
    }
    const bool grow = (pmax[0] > mst[0] + 8.f) | (pmax[1] > mst[1] + 8.f) |
                      (pmax[2] > mst[2] + 8.f) | (pmax[3] > mst[3] + 8.f);
    if (__any(grow)) {
#pragma unroll
      for (int rg = 0; rg < 4; ++rg) {
        const float mnew = fmaxf(mst[rg], pmax[rg]);
        const float alpha = exp2f(mst[rg] - mnew);
        mst[rg] = mnew;
        lst[rg] *= alpha;
#pragma unroll
        for (int df = 0; df < 8; ++df) o[df][rg] *= alpha;
      }
    }
#pragma unroll
    for (int rg = 0; rg < 4; ++rg) {
      float rsum = 0.f;
#pragma unroll
      for (int cf = 0; cf < 4; ++cf) {
        const float p = exp2f(sacc[cf][rg] - mst[rg]);
        sacc[cf][rg] = p;
        rsum += p;
      }
      rsum += __shfl_xor(rsum, 1);
      rsum += __shfl_xor(rsum, 2);
      rsum += __shfl_xor(rsum, 4);
      rsum += __shfl_xor(rsum, 8);
      lst[rg] += rsum;
    }

    // P -> per-wave LDS (A-frag layout [16][72]); same-wave write->read
#pragma unroll
    for (int cf = 0; cf < 4; ++cf)
#pragma unroll
      for (int rg = 0; rg < 4; ++rg)
        lsP[(lk * 4 + rg) * 72 + cf * 16 + lrow] = to_bf16(sacc[cf][rg]);
    // PV
#pragma unroll
    for (int k2 = 0; k2 < 2; ++k2) {
      const bf16x8 aP = *reinterpret_cast<const bf16x8*>(
          &lsP[lrow * 72 + k2 * 32 + lk * 8]);
#pragma unroll
      for (int df = 0; df < 8; ++df) {
        const int row = df * 16 + lrow;
        const int colb = (k2 * 32 + lk * 8) ^ (((row >> 3) & 7) << 3);
        const bf16x8 bV = *reinterpret_cast<const bf16x8*>(&lsV[row * 72 + colb]);
        o[df] = MFMA16(aP, bV, o[df]);
      }
    }
  }

  // normalize + write y [b][t][h*128+d]
#pragma unroll
  for (int rg = 0; rg < 4; ++rg) {
    const float inv = 1.0f / lst[rg];
    const int qi = qbase + lk * 4 + rg;
    const size_t rowoff = ((size_t)(b * 2048 + qi)) * 2048 + h * 128;
#pragma unroll
    for (int df = 0; df < 8; ++df)
      y[rowoff + df * 16 + lrow] = to_bf16(o[df][rg] * inv);
  }
}

// ---------------------------------------------------------------------------
extern "C" void kernel_launch(void* const* d_in, const int* in_sizes, int n_in,
                              void* d_out, int out_size, void* d_ws, size_t ws_size,
                              hipStream_t stream) {
  const float* x  = (const float*)d_in[0];
  const float* ve = (const float*)d_in[1];
  const float* Wq = (const float*)d_in[2];
  const float* Wk = (const float*)d_in[3];
  const float* Wv = (const float*)d_in[4];
  const float* Wp = (const float*)d_in[5];
  const float* qg = (const float*)d_in[6];
  float* out = (float*)d_out;

  char* ws = (char*)d_ws;
  size_t off = 0;
  auto alloc = [&](size_t bytes) -> char* {
    char* p = ws + off;
    off += (bytes + 255) & ~(size_t)255;
    return p;
  };

  bf16_t* x2     = (bf16_t*)alloc((size_t)4096 * 4096 * 2);  // [xh|xl]; later qn2
  bf16_t* wqkv2  = (bf16_t*)alloc((size_t)3072 * 4096 * 2);  // rows Wq|Wk|Wv, [Wh|Wl]
  bf16_t* wpb    = (bf16_t*)alloc((size_t)2048 * 2048 * 2);
  float*  qkvraw = (float*)alloc((size_t)4096 * 3072 * 4);   // later yb
  bf16_t* kn     = (bf16_t*)alloc((size_t)2 * 4 * 2048 * 128 * 2);
  bf16_t* vn     = (bf16_t*)alloc((size_t)2 * 4 * 2048 * 128 * 2);
  float*  ctab   = (float*)alloc((size_t)2048 * 32 * 4);
  float*  stab   = (float*)alloc((size_t)2048 * 32 * 4);
  bf16_t* qn2    = x2;               // x2 dead after QKV GEMM (32MB = 32MB)
  bf16_t* yb     = (bf16_t*)qkvraw;  // qkvraw dead after epilogue
  (void)ws_size; (void)in_sizes; (void)n_in; (void)out_size;

  k_split_x<<<2048, 256, 0, stream>>>(x, x2);
  k_split_w<<<1024, 256, 0, stream>>>(Wq, wqkv2, (long)2048 * 2048);
  k_split_w<<<512,  256, 0, stream>>>(Wk, wqkv2 + (size_t)2048 * 4096, (long)512 * 2048);
  k_split_w<<<512,  256, 0, stream>>>(Wv, wqkv2 + (size_t)2560 * 4096, (long)512 * 2048);
  k_cast_bf16<<<1024, 256, 0, stream>>>(Wp, wpb, (long)2048 * 2048);
  k_rope_tab<<<256, 256, 0, stream>>>(ctab, stab);

  // qkvraw = [xh|xl|xh]·[Wh|Wh|Wl]^T  (M=4096 N=3072 K=6144 virtual; 256x192)
  k_gemmQ<3><<<dim3(16, 16), 512, 0, stream>>>(x2, wqkv2, qkvraw, 4096, 3072, 6144, 4096, 4096);

  k_qkv_epi<<<4096, 256, 0, stream>>>(qkvraw, ve, qg, ctab, stab, qn2, kn, vn);

  k_attn<<<dim3(32, 32), 256, 0, stream>>>(qn2, kn, vn, yb);

  // out = y · Wp^T  (M=4096 N=2048 K=2048; 256x128)
  k_gemmQ<2><<<dim3(16, 16), 512, 0, stream>>>(yb, wpb, out, 4096, 2048, 2048, 2048, 2048);
}

// Round 10
// 318.098 us; speedup vs baseline: 1.1892x; 1.0247x over previous
//
#include <hip/hip_runtime.h>
#include <hip/hip_bf16.h>
#include <cstdint>
#include <cstddef>

// ---------------------------------------------------------------------------
// CausalSelfAttention fused block, MI355X/gfx950.  Round 10:
//  - GEMMs: 1024 threads / 16 waves per block (4 waves/SIMD with 112KB LDS;
//    R9's 512-thr variant was occupancy-capped at 2 waves/SIMD -> 45% Mfma).
//    Staging by waves 0-7 only; same 2-phase counted-vmcnt schedule.
//  - merged W-split kernel (1 launch instead of 3).
//  - attn/epilogue unchanged (R5-proven attn).
// B=2 T=2048 D=2048 NH=16 NKV=4 HD=128 ROPE=64.
// ---------------------------------------------------------------------------

typedef __bf16 bf16_t;
typedef bf16_t bf16x8 __attribute__((ext_vector_type(8)));
typedef float f32x4 __attribute__((ext_vector_type(4)));

#define MFMA16(a, b, c) __builtin_amdgcn_mfma_f32_16x16x32_bf16((a), (b), (c), 0, 0, 0)
#define SBAR()   __builtin_amdgcn_s_barrier()
#define SCHED0() __builtin_amdgcn_sched_barrier(0)
#define LGKM0()  asm volatile("s_waitcnt lgkmcnt(0)" ::: "memory")

__device__ __forceinline__ bf16_t to_bf16(float f) {
  __hip_bfloat16 h = __float2bfloat16(f);
  return *reinterpret_cast<bf16_t*>(&h);
}

__device__ __forceinline__ void gload16(const bf16_t* g, bf16_t* l) {
  auto lds_ptr = reinterpret_cast<__attribute__((address_space(3))) unsigned int*>(
      reinterpret_cast<uintptr_t>(l));
  auto g_ptr = reinterpret_cast<const __attribute__((address_space(1))) unsigned int*>(
      reinterpret_cast<uintptr_t>(g));
  __builtin_amdgcn_global_load_lds(g_ptr, lds_ptr, 16, 0, 0);
}

// ---------------------------------------------------------------------------
// fp32 -> bf16 cast, vectorized
// ---------------------------------------------------------------------------
__global__ void k_cast_bf16(const float* __restrict__ in, bf16_t* __restrict__ o, long n) {
  long i = ((long)blockIdx.x * blockDim.x + threadIdx.x) * 4;
  const long step = (long)gridDim.x * blockDim.x * 4;
  for (; i < n; i += step) {
    const float4 v = *reinterpret_cast<const float4*>(in + i);
    bf16_t r[4] = {to_bf16(v.x), to_bf16(v.y), to_bf16(v.z), to_bf16(v.w)};
    *reinterpret_cast<uint64_t*>(o + i) = *reinterpret_cast<const uint64_t*>(r);
  }
}

// ---------------------------------------------------------------------------
// x split: in [4096][2048] fp32 -> x2 [4096][4096] bf16 = [xh | xl]
// ---------------------------------------------------------------------------
__global__ void k_split_x(const float* __restrict__ in, bf16_t* __restrict__ x2) {
  long i = ((long)blockIdx.x * blockDim.x + threadIdx.x) * 4;
  const long step = (long)gridDim.x * blockDim.x * 4;
  for (; i < (long)4096 * 2048; i += step) {
    const float4 v = *reinterpret_cast<const float4*>(in + i);
    const long row = i >> 11, col = i & 2047;
    bf16_t h[4], l[4];
    const float vv[4] = {v.x, v.y, v.z, v.w};
#pragma unroll
    for (int j = 0; j < 4; ++j) {
      h[j] = to_bf16(vv[j]);
      l[j] = to_bf16(vv[j] - (float)h[j]);
    }
    bf16_t* rp = x2 + row * 4096;
    *reinterpret_cast<uint64_t*>(rp + col) = *reinterpret_cast<const uint64_t*>(h);
    *reinterpret_cast<uint64_t*>(rp + 2048 + col) = *reinterpret_cast<const uint64_t*>(l);
  }
}

// ---------------------------------------------------------------------------
// merged W split: rows 0-2047 Wq, 2048-2559 Wk, 2560-3071 Wv ->
// wqkv2 [3072][4096] = [Wh | Wl] per row.
// ---------------------------------------------------------------------------
__global__ void k_split_wqkv(const float* __restrict__ Wq, const float* __restrict__ Wk,
                             const float* __restrict__ Wv, bf16_t* __restrict__ w2) {
  long i = ((long)blockIdx.x * blockDim.x + threadIdx.x) * 4;
  const long step = (long)gridDim.x * blockDim.x * 4;
  for (; i < (long)3072 * 2048; i += step) {
    const long row = i >> 11, col = i & 2047;
    const float* src = (row < 2048) ? (Wq + (size_t)row * 2048)
                     : (row < 2560) ? (Wk + (size_t)(row - 2048) * 2048)
                                    : (Wv + (size_t)(row - 2560) * 2048);
    const float4 v = *reinterpret_cast<const float4*>(src + col);
    bf16_t h[4], l[4];
    const float vv[4] = {v.x, v.y, v.z, v.w};
#pragma unroll
    for (int j = 0; j < 4; ++j) {
      h[j] = to_bf16(vv[j]);
      l[j] = to_bf16(vv[j] - (float)h[j]);
    }
    bf16_t* rp = w2 + row * 4096;
    *reinterpret_cast<uint64_t*>(rp + col) = *reinterpret_cast<const uint64_t*>(h);
    *reinterpret_cast<uint64_t*>(rp + 2048 + col) = *reinterpret_cast<const uint64_t*>(l);
  }
}

// ---------------------------------------------------------------------------
// RoPE cos/sin table: [T=2048][32]
// ---------------------------------------------------------------------------
__global__ void k_rope_tab(float* __restrict__ ctab, float* __restrict__ stab) {
  const int idx = blockIdx.x * blockDim.x + threadIdx.x;
  if (idx >= 2048 * 32) return;
  const int t = idx >> 5, i = idx & 31;
  const float freq = exp2f(-(float)i * 0.2076205059304601f);  // 10000^(-i/64)
  const float f = (float)t * freq;
  ctab[idx] = cosf(f);
  stab[idx] = sinf(f);
}

// ---------------------------------------------------------------------------
// 256 x (64*NBU) NT GEMM, 1024 threads = 16 waves (4M x 4N), wave-tile
// 64 x (16*NBU); BK=64.  A'(k) = A col (k>=4096 ? k-4096 : k); B'(k) = B col
// (k>=2048 ? k-2048 : k)  (no-ops when K<=2048).  LDS = 2 bufs x (4+NBU)
// units of 64x64, slot-XOR swizzle (slot ^= row&7), global_load_lds 16B
// issued by waves 0-7 only (tid<512).  2-phase counted-vmcnt schedule.
// Requires M%256==0, N%(64*NBU)==0, K%64==0, nkt>=2, grid (N/(64*NBU),
// M/256), nwg%8==0.
// ---------------------------------------------------------------------------
template <int NBU>
__global__ __launch_bounds__(1024, 1) void k_gemmQ(
    const bf16_t* __restrict__ A, const bf16_t* __restrict__ Bm,
    float* __restrict__ C, int M, int N, int K, int lda, int ldb)
{
  __shared__ __align__(16) bf16_t lds[2][(4 + NBU) * 4096];
  const int tid = threadIdx.x;
  const int l = tid & 63, w = tid >> 6;       // w 0..15
  const int lrow = l & 15, lk = l >> 4;
  const int wm = w >> 2, wn = w & 3;          // 4 x 4 wave grid

  const int nwg = gridDim.x * gridDim.y;
  int lin = blockIdx.y * gridDim.x + blockIdx.x;
  lin = (lin & 7) * (nwg >> 3) + (lin >> 3);
  const int m0 = (lin / gridDim.x) * 256, n0 = (lin % gridDim.x) * (64 * NBU);

  // staging (waves 0-7): thread -> (unit-row tid>>3, phys slot tid&7);
  // src col = (slot ^ row&7)*8
  const bool stager = (tid < 512);
  const int srow = tid >> 3;
  const int scol = ((tid & 7) ^ (srow & 7)) << 3;
  const bf16_t* gP[4 + NBU];
#pragma unroll
  for (int u = 0; u < 4; ++u) gP[u] = A + (size_t)(m0 + u * 64 + srow) * lda + scol;
#pragma unroll
  for (int u = 0; u < NBU; ++u) gP[4 + u] = Bm + (size_t)(n0 + u * 64 + srow) * ldb + scol;

  auto stageAll = [&](int buf, int k0) {
    const int kA = (k0 >= 4096) ? k0 - 4096 : k0;   // [xh|xl|xh] virtual
    const int kB = (k0 >= 2048) ? k0 - 2048 : k0;   // [Wh|Wh|Wl] virtual
#pragma unroll
    for (int u = 0; u < 4 + NBU; ++u)
      gload16(gP[u] + (u < 4 ? kA : kB), &lds[buf][u * 4096 + tid * 8]);
  };
  auto rdA = [&](int buf, int mf, int ks) -> bf16x8 {
    const int row = wm * 64 + mf * 16 + lrow;             // 0..255
    const int slot = ((ks << 2) | lk) ^ (row & 7);
    return *reinterpret_cast<const bf16x8*>(&lds[buf][row * 64 + slot * 8]);
  };
  auto rdB = [&](int buf, int nf, int ks) -> bf16x8 {
    const int row = wn * (16 * NBU) + nf * 16 + lrow;     // 0..64*NBU-1
    const int slot = ((ks << 2) | lk) ^ (row & 7);
    return *reinterpret_cast<const bf16x8*>(&lds[buf][16384 + row * 64 + slot * 8]);
  };

  f32x4 acc[4][NBU] = {};
  const int nkt = K >> 6;

  if (stager) {
    stageAll(0, 0);
    stageAll(1, nkt > 1 ? 64 : 0);
  }
  if constexpr (NBU == 3) { asm volatile("s_waitcnt vmcnt(7)" ::: "memory"); }
  else                    { asm volatile("s_waitcnt vmcnt(6)" ::: "memory"); }
  SCHED0();
  SBAR(); SCHED0();

  bf16x8 aA[4][2], bB[NBU][2];
  for (int kt = 0; kt < nkt; ++kt) {
    const int b = kt & 1;
    const int kn2 = (kt + 2 < nkt ? kt + 2 : nkt - 1) << 6;

    // phase 1: read all frags of tile t, MFMA mf 0..1
#pragma unroll
    for (int mf = 0; mf < 4; ++mf) { aA[mf][0] = rdA(b, mf, 0); aA[mf][1] = rdA(b, mf, 1); }
#pragma unroll
    for (int nf = 0; nf < NBU; ++nf) { bB[nf][0] = rdB(b, nf, 0); bB[nf][1] = rdB(b, nf, 1); }
    __builtin_amdgcn_s_setprio(1);
#pragma unroll
    for (int mf = 0; mf < 2; ++mf)
#pragma unroll
      for (int nf = 0; nf < NBU; ++nf)
#pragma unroll
        for (int ks = 0; ks < 2; ++ks)
          acc[mf][nf] = MFMA16(aA[mf][ks], bB[nf][ks], acc[mf][nf]);
    __builtin_amdgcn_s_setprio(0);
    LGKM0(); SCHED0();       // all my ds_reads of buf b complete
    SBAR(); SCHED0();        // ... on every wave -> safe to overwrite buf b

    // phase 2: stage tile t+2 over dead buf b; wait tile t+1; MFMA mf 2..3
    if (stager) stageAll(b, kn2);
    if constexpr (NBU == 3) { asm volatile("s_waitcnt vmcnt(7)" ::: "memory"); }
    else                    { asm volatile("s_waitcnt vmcnt(6)" ::: "memory"); }
    SCHED0();
    __builtin_amdgcn_s_setprio(1);
#pragma unroll
    for (int mf = 2; mf < 4; ++mf)
#pragma unroll
      for (int nf = 0; nf < NBU; ++nf)
#pragma unroll
        for (int ks = 0; ks < 2; ++ks)
          acc[mf][nf] = MFMA16(aA[mf][ks], bB[nf][ks], acc[mf][nf]);
    __builtin_amdgcn_s_setprio(0);
    SBAR(); SCHED0();        // all waves past vmcnt -> t+1 resident for next reads
  }

  // C-write: row = m0 + wm*64 + mf*16 + lk*4 + rg ; col = n0 + wn*16*NBU + nf*16 + lrow
#pragma unroll
  for (int mf = 0; mf < 4; ++mf) {
    const int row = m0 + wm * 64 + mf * 16 + lk * 4;
#pragma unroll
    for (int nf = 0; nf < NBU; ++nf) {
      const int col = n0 + wn * (16 * NBU) + nf * 16 + lrow;
#pragma unroll
      for (int rg = 0; rg < 4; ++rg)
        C[(size_t)(row + rg) * N + col] = acc[mf][nf][rg];
    }
  }
  (void)M;
}

// ---------------------------------------------------------------------------
// QKV epilogue.  qkv raw = [4096][3072] f32 (q | k | v).  RMS-norm(q,k) +
// partial RoPE in fp32; q gets gain*(1/sqrt(128))*log2(e) folded in, stored
// hi/lo bf16 [.][256]; k plain bf16 [.][128]; v += ve_embed, plain bf16.
// ---------------------------------------------------------------------------
__global__ __launch_bounds__(256) void k_qkv_epi(
    const float* __restrict__ qkv, const float* __restrict__ ve,
    const float* __restrict__ qgain,
    const float* __restrict__ ctab, const float* __restrict__ stab,
    bf16_t* __restrict__ qn2, bf16_t* __restrict__ kn, bf16_t* __restrict__ vn)
{
  const int blk = blockIdx.x;           // b*2048 + t
  const int b = blk >> 11, t = blk & 2047;
  const int w = threadIdx.x >> 6, l = threadIdx.x & 63;
  const int i32 = l & 31;
  const float c = ctab[t * 32 + i32], s = stab[t * 32 + i32];
  const float EPS = 1.1920929e-07f;
  constexpr float SCALE_L2E = 0.088388347648318447f * 1.4426950408889634f;

  // Q: wave w handles heads w, w+4, w+8, w+12
#pragma unroll
  for (int it = 0; it < 4; ++it) {
    const int h = w + it * 4;
    const float* row = qkv + (size_t)blk * 3072 + h * 128;
    float x0 = row[l], x1 = row[l + 64];
    float ss = x0 * x0 + x1 * x1;
#pragma unroll
    for (int off = 32; off; off >>= 1) ss += __shfl_xor(ss, off);
    const float rn = rsqrtf(ss * (1.0f / 128.0f) + EPS);
    x0 *= rn; x1 *= rn;
    const float p = __shfl_xor(x0, 32);
    float xr = (l < 32) ? (x0 * c - p * s) : (p * s + x0 * c);
    const float g = qgain[h] * SCALE_L2E;
    xr *= g; x1 *= g;
    bf16_t* orow = qn2 + (((size_t)(b * 16 + h)) * 2048 + t) * 256;
    const bf16_t h0 = to_bf16(xr), h1 = to_bf16(x1);
    orow[l] = h0;        orow[128 + l] = to_bf16(xr - (float)h0);
    orow[l + 64] = h1;   orow[192 + l] = to_bf16(x1 - (float)h1);
  }
  // K: wave w -> kv head w (plain bf16)
  {
    const float* row = qkv + (size_t)blk * 3072 + 2048 + w * 128;
    float x0 = row[l], x1 = row[l + 64];
    float ss = x0 * x0 + x1 * x1;
#pragma unroll
    for (int off = 32; off; off >>= 1) ss += __shfl_xor(ss, off);
    const float rn = rsqrtf(ss * (1.0f / 128.0f) + EPS);
    x0 *= rn; x1 *= rn;
    const float p = __shfl_xor(x0, 32);
    const float xr = (l < 32) ? (x0 * c - p * s) : (p * s + x0 * c);
    bf16_t* orow = kn + (((size_t)(b * 4 + w)) * 2048 + t) * 128;
    orow[l] = to_bf16(xr);
    orow[l + 64] = to_bf16(x1);
  }
  // V: wave w -> kv head w ; v = vraw + ve
  {
    const float* row = qkv + (size_t)blk * 3072 + 2560 + w * 128;
    const float* verow = ve + (size_t)blk * 512 + w * 128;
    bf16_t* orow = vn + (((size_t)(b * 4 + w)) * 2048 + t) * 128;
    orow[l] = to_bf16(row[l] + verow[l]);
    orow[l + 64] = to_bf16(row[l + 64] + verow[l + 64]);
  }
}

// ---------------------------------------------------------------------------
// Causal GQA flash attention (R5 kernel, proven).  q hi/lo (2-term S), k
// plain.  QBLK=64 (4 waves x 16 q-rows), KVBLK=64, longest-qt-first.
// LDS: lsK [64][136] padded (2-way reads), lsV^T [128][72] XOR-swizzled,
// lsP per-wave [16][72].  45KB -> 3 blocks/CU.  2 barriers/tile.  K+V
// prefetched into registers one tile ahead.
// ---------------------------------------------------------------------------
__global__ __launch_bounds__(256, 3) void k_attn(
    const bf16_t* __restrict__ qn2, const bf16_t* __restrict__ kn,
    const bf16_t* __restrict__ vn, bf16_t* __restrict__ y)
{
  __shared__ __align__(16) bf16_t lsK[64 * 136];      // 17408 B
  __shared__ __align__(16) bf16_t lsV[128 * 72];      // 18432 B
  __shared__ __align__(16) bf16_t lsPb[4][16 * 72];   //  9216 B
  const int qt = 31 - (int)blockIdx.y;  // longest first
  const int bh = blockIdx.x;            // 0..31
  const int b = bh >> 4, h = bh & 15, kvh = h >> 2;
  const int tid = threadIdx.x, w = tid >> 6, l = tid & 63;
  const int lrow = l & 15, lk = l >> 4;
  const int qbase = qt * 64 + w * 16;
  constexpr float NEG = -1e30f;
  bf16_t* lsP = lsPb[w];

  // Q fragments (A-frag: row = lane&15, k = lk*8+j), hi and lo
  const bf16_t* qp = qn2 + ((size_t)(b * 16 + h) * 2048) * 256;
  bf16x8 aQh[4], aQl[4];
#pragma unroll
  for (int kf = 0; kf < 4; ++kf) {
    const size_t base = (size_t)(qbase + lrow) * 256 + kf * 32 + lk * 8;
    aQh[kf] = *reinterpret_cast<const bf16x8*>(qp + base);
    aQl[kf] = *reinterpret_cast<const bf16x8*>(qp + base + 128);
  }

  const bf16_t* kp = kn + ((size_t)(b * 4 + kvh) * 2048) * 128;
  const bf16_t* vp = vn + ((size_t)(b * 4 + kvh) * 2048) * 128;

  f32x4 o[8] = {};
  float mst[4], lst[4];
#pragma unroll
  for (int rg = 0; rg < 4; ++rg) { mst[rg] = NEG; lst[rg] = 0.f; }

  // K/V register prefetch (tile t0): chunk cch = tid + it*256,
  // row = cch>>4 (0..63), slot = cch&15.
  bf16x8 kreg[4], vreg[4];
  auto loadKV = [&](int t0) {
#pragma unroll
    for (int it = 0; it < 4; ++it) {
      const int cch = tid + it * 256;
      const size_t goff = (size_t)(t0 + (cch >> 4)) * 128 + (cch & 15) * 8;
      kreg[it] = *reinterpret_cast<const bf16x8*>(kp + goff);
      vreg[it] = *reinterpret_cast<const bf16x8*>(vp + goff);
    }
  };
  loadKV(0);

  const int ntiles = qt + 1;
  for (int tt = 0; tt < ntiles; ++tt) {
    __syncthreads();  // prior tile's K/V LDS reads done before restage
    // stage K [64][136] + V^T [128][72] (col' = kv ^ ((dg&7)<<3)) from regs
#pragma unroll
    for (int it = 0; it < 4; ++it) {
      const int cch = tid + it * 256;
      const int r = cch >> 4, dg = cch & 15;
      *reinterpret_cast<bf16x8*>(&lsK[r * 136 + dg * 8]) = kreg[it];
      const int colb = r ^ ((dg & 7) << 3);
#pragma unroll
      for (int j = 0; j < 8; ++j) lsV[(dg * 8 + j) * 72 + colb] = vreg[it][j];
    }
    // prefetch next tile's K/V (in flight across S + softmax + PV)
    if (tt + 1 < ntiles) loadKV((tt + 1) * 64);
    __syncthreads();  // staged data visible

    // S = Qh*Kh + Ql*Kh  (16 q-rows x 64 kv)
    f32x4 sacc[4] = {};
#pragma unroll
    for (int cf = 0; cf < 4; ++cf) {
      const int krow = cf * 16 + lrow;
#pragma unroll
      for (int kf = 0; kf < 4; ++kf) {
        const bf16x8 bK = *reinterpret_cast<const bf16x8*>(
            &lsK[krow * 136 + kf * 32 + lk * 8]);
        sacc[cf] = MFMA16(aQh[kf], bK, sacc[cf]);
        sacc[cf] = MFMA16(aQl[kf], bK, sacc[cf]);
      }
    }

    // online softmax, log2 domain; mask only on diagonal tile
    if (tt == qt) {
#pragma unroll
      for (int rg = 0; rg < 4; ++rg) {
        const int qi = w * 16 + lk * 4 + rg;  // within-tile row
#pragma unroll
        for (int cf = 0; cf < 4; ++cf)
          if (cf * 16 + lrow > qi) sacc[cf][rg] = NEG;
      }
    }
    float pmax[4];
#pragma unroll
    for (int rg = 0; rg < 4; ++rg) {
      float mx = fmaxf(fmaxf(sacc[0][rg], sacc[1][rg]),
                       fmaxf(sacc[2][rg], sacc[3][rg]));
      mx = fmaxf(mx, __shfl_xor(mx, 1));
      mx = fmaxf(mx, __shfl_xor(mx, 2));
      mx = fmaxf(mx, __shfl_xor(mx, 4));
      mx = fmaxf(mx, __shfl_xor(mx, 8));
      pmax[rg] = mx;
    }
    const bool grow = (pmax[0] > mst[0] + 8.f) | (pmax[1] > mst[1] + 8.f) |
                      (pmax[2] > mst[2] + 8.f) | (pmax[3] > mst[3] + 8.f);
    if (__any(grow)) {
#pragma unroll
      for (int rg = 0; rg < 4; ++rg) {
        const float mnew = fmaxf(mst[rg], pmax[rg]);
        const float alpha = exp2f(mst[rg] - mnew);
        mst[rg] = mnew;
        lst[rg] *= alpha;
#pragma unroll
        for (int df = 0; df < 8; ++df) o[df][rg] *= alpha;
      }
    }
#pragma unroll
    for (int rg = 0; rg < 4; ++rg) {
      float rsum = 0.f;
#pragma unroll
      for (int cf = 0; cf < 4; ++cf) {
        const float p = exp2f(sacc[cf][rg] - mst[rg]);
        sacc[cf][rg] = p;
        rsum += p;
      }
      rsum += __shfl_xor(rsum, 1);
      rsum += __shfl_xor(rsum, 2);
      rsum += __shfl_xor(rsum, 4);
      rsum += __shfl_xor(rsum, 8);
      lst[rg] += rsum;
    }

    // P -> per-wave LDS (A-frag layout [16][72]); same-wave write->read
#pragma unroll
    for (int cf = 0; cf < 4; ++cf)
#pragma unroll
      for (int rg = 0; rg < 4; ++rg)
        lsP[(lk * 4 + rg) * 72 + cf * 16 + lrow] = to_bf16(sacc[cf][rg]);
    // PV
#pragma unroll
    for (int k2 = 0; k2 < 2; ++k2) {
      const bf16x8 aP = *reinterpret_cast<const bf16x8*>(
          &lsP[lrow * 72 + k2 * 32 + lk * 8]);
#pragma unroll
      for (int df = 0; df < 8; ++df) {
        const int row = df * 16 + lrow;
        const int colb = (k2 * 32 + lk * 8) ^ (((row >> 3) & 7) << 3);
        const bf16x8 bV = *reinterpret_cast<const bf16x8*>(&lsV[row * 72 + colb]);
        o[df] = MFMA16(aP, bV, o[df]);
      }
    }
  }

  // normalize + write y [b][t][h*128+d]
#pragma unroll
  for (int rg = 0; rg < 4; ++rg) {
    const float inv = 1.0f / lst[rg];
    const int qi = qbase + lk * 4 + rg;
    const size_t rowoff = ((size_t)(b * 2048 + qi)) * 2048 + h * 128;
#pragma unroll
    for (int df = 0; df < 8; ++df)
      y[rowoff + df * 16 + lrow] = to_bf16(o[df][rg] * inv);
  }
}

// ---------------------------------------------------------------------------
extern "C" void kernel_launch(void* const* d_in, const int* in_sizes, int n_in,
                              void* d_out, int out_size, void* d_ws, size_t ws_size,
                              hipStream_t stream) {
  const float* x  = (const float*)d_in[0];
  const float* ve = (const float*)d_in[1];
  const float* Wq = (const float*)d_in[2];
  const float* Wk = (const float*)d_in[3];
  const float* Wv = (const float*)d_in[4];
  const float* Wp = (const float*)d_in[5];
  const float* qg = (const float*)d_in[6];
  float* out = (float*)d_out;

  char* ws = (char*)d_ws;
  size_t off = 0;
  auto alloc = [&](size_t bytes) -> char* {
    char* p = ws + off;
    off += (bytes + 255) & ~(size_t)255;
    return p;
  };

  bf16_t* x2     = (bf16_t*)alloc((size_t)4096 * 4096 * 2);  // [xh|xl]; later qn2
  bf16_t* wqkv2  = (bf16_t*)alloc((size_t)3072 * 4096 * 2);  // rows Wq|Wk|Wv, [Wh|Wl]
  bf16_t* wpb    = (bf16_t*)alloc((size_t)2048 * 2048 * 2);
  float*  qkvraw = (float*)alloc((size_t)4096 * 3072 * 4);   // later yb
  bf16_t* kn     = (bf16_t*)alloc((size_t)2 * 4 * 2048 * 128 * 2);
  bf16_t* vn     = (bf16_t*)alloc((size_t)2 * 4 * 2048 * 128 * 2);
  float*  ctab   = (float*)alloc((size_t)2048 * 32 * 4);
  float*  stab   = (float*)alloc((size_t)2048 * 32 * 4);
  bf16_t* qn2    = x2;               // x2 dead after QKV GEMM (32MB = 32MB)
  bf16_t* yb     = (bf16_t*)qkvraw;  // qkvraw dead after epilogue
  (void)ws_size; (void)in_sizes; (void)n_in; (void)out_size;

  k_split_x<<<2048, 256, 0, stream>>>(x, x2);
  k_split_wqkv<<<1536, 256, 0, stream>>>(Wq, Wk, Wv, wqkv2);
  k_cast_bf16<<<1024, 256, 0, stream>>>(Wp, wpb, (long)2048 * 2048);
  k_rope_tab<<<256, 256, 0, stream>>>(ctab, stab);

  // qkvraw = [xh|xl|xh]·[Wh|Wh|Wl]^T  (M=4096 N=3072 K=6144 virtual; 256x192)
  k_gemmQ<3><<<dim3(16, 16), 1024, 0, stream>>>(x2, wqkv2, qkvraw, 4096, 3072, 6144, 4096, 4096);

  k_qkv_epi<<<4096, 256, 0, stream>>>(qkvraw, ve, qg, ctab, stab, qn2, kn, vn);

  k_attn<<<dim3(32, 32), 256, 0, stream>>>(qn2, kn, vn, yb);

  // out = y · Wp^T  (M=4096 N=2048 K=2048; 256x128)
  k_gemmQ<2><<<dim3(16, 16), 1024, 0, stream>>>(yb, wpb, out, 4096, 2048, 2048, 2048, 2048);
}

// Round 11
// 216.072 us; speedup vs baseline: 1.7507x; 1.4722x over previous
//
#include <hip/hip_runtime.h>
#include <hip/hip_bf16.h>
#include <cstdint>
#include <cstddef>

// ---------------------------------------------------------------------------
// CausalSelfAttention fused block, MI355X/gfx950.  Round 11:
//  - fp16 (10-bit mantissa) replaces bf16 hi/lo split everywhere on the
//    logit chain: QKV GEMM is single-pass K=2048 (was 6144), attn S is
//    single-term (was 2-term), q stored plain (was hi|lo).  8x less rounding
//    error than bf16 => absmax ~0.03 vs 0.13 threshold, 3x less GEMM work.
//  - GEMM: 256x192 / 256x128 tiles, 16 waves, 2-phase counted-vmcnt (R10).
//  - attn: R5 structure, fp16, 16 S-MFMA + 16 PV-MFMA per wave-tile.
// B=2 T=2048 D=2048 NH=16 NKV=4 HD=128 ROPE=64.
// ---------------------------------------------------------------------------

typedef _Float16 f16_t;
typedef f16_t f16x8 __attribute__((ext_vector_type(8)));
typedef float f32x4 __attribute__((ext_vector_type(4)));

#define MFMA16F(a, b, c) __builtin_amdgcn_mfma_f32_16x16x32_f16((a), (b), (c), 0, 0, 0)
#define SBAR()   __builtin_amdgcn_s_barrier()
#define SCHED0() __builtin_amdgcn_sched_barrier(0)
#define LGKM0()  asm volatile("s_waitcnt lgkmcnt(0)" ::: "memory")

__device__ __forceinline__ void gload16(const f16_t* g, f16_t* l) {
  auto lds_ptr = reinterpret_cast<__attribute__((address_space(3))) unsigned int*>(
      reinterpret_cast<uintptr_t>(l));
  auto g_ptr = reinterpret_cast<const __attribute__((address_space(1))) unsigned int*>(
      reinterpret_cast<uintptr_t>(g));
  __builtin_amdgcn_global_load_lds(g_ptr, lds_ptr, 16, 0, 0);
}

// ---------------------------------------------------------------------------
// fp32 -> fp16 cast, vectorized
// ---------------------------------------------------------------------------
__global__ void k_cast_f16(const float* __restrict__ in, f16_t* __restrict__ o, long n) {
  long i = ((long)blockIdx.x * blockDim.x + threadIdx.x) * 4;
  const long step = (long)gridDim.x * blockDim.x * 4;
  for (; i < n; i += step) {
    const float4 v = *reinterpret_cast<const float4*>(in + i);
    f16_t r[4] = {(f16_t)v.x, (f16_t)v.y, (f16_t)v.z, (f16_t)v.w};
    *reinterpret_cast<uint64_t*>(o + i) = *reinterpret_cast<const uint64_t*>(r);
  }
}

// ---------------------------------------------------------------------------
// merged W cast: rows 0-2047 Wq, 2048-2559 Wk, 2560-3071 Wv -> wf [3072][2048]
// ---------------------------------------------------------------------------
__global__ void k_cast_wqkv(const float* __restrict__ Wq, const float* __restrict__ Wk,
                            const float* __restrict__ Wv, f16_t* __restrict__ wf) {
  long i = ((long)blockIdx.x * blockDim.x + threadIdx.x) * 4;
  const long step = (long)gridDim.x * blockDim.x * 4;
  for (; i < (long)3072 * 2048; i += step) {
    const long row = i >> 11, col = i & 2047;
    const float* src = (row < 2048) ? (Wq + (size_t)row * 2048)
                     : (row < 2560) ? (Wk + (size_t)(row - 2048) * 2048)
                                    : (Wv + (size_t)(row - 2560) * 2048);
    const float4 v = *reinterpret_cast<const float4*>(src + col);
    f16_t r[4] = {(f16_t)v.x, (f16_t)v.y, (f16_t)v.z, (f16_t)v.w};
    *reinterpret_cast<uint64_t*>(wf + row * 2048 + col) = *reinterpret_cast<const uint64_t*>(r);
  }
}

// ---------------------------------------------------------------------------
// RoPE cos/sin table: [T=2048][32]
// ---------------------------------------------------------------------------
__global__ void k_rope_tab(float* __restrict__ ctab, float* __restrict__ stab) {
  const int idx = blockIdx.x * blockDim.x + threadIdx.x;
  if (idx >= 2048 * 32) return;
  const int t = idx >> 5, i = idx & 31;
  const float freq = exp2f(-(float)i * 0.2076205059304601f);  // 10000^(-i/64)
  const float f = (float)t * freq;
  ctab[idx] = cosf(f);
  stab[idx] = sinf(f);
}

// ---------------------------------------------------------------------------
// 256 x (64*NBU) NT GEMM, fp16 in, OutT out: C[m,n] = sum_k A[m,k]*B[n,k].
// 1024 threads = 16 waves (4M x 4N), wave-tile 64 x (16*NBU); BK=64.
// LDS = 2 bufs x (4+NBU) units of 64x64, slot-XOR swizzle (slot ^= row&7),
// global_load_lds 16B issued by waves 0-7 (tid<512).  2-phase counted-vmcnt.
// Requires M%256==0, N%(64*NBU)==0, K%64==0, nkt>=2, grid (N/(64*NBU),
// M/256), nwg%8==0.
// ---------------------------------------------------------------------------
template <int NBU, typename OutT>
__global__ __launch_bounds__(1024, 1) void k_gemmQ(
    const f16_t* __restrict__ A, const f16_t* __restrict__ Bm,
    OutT* __restrict__ C, int M, int N, int K, int lda, int ldb)
{
  __shared__ __align__(16) f16_t lds[2][(4 + NBU) * 4096];
  const int tid = threadIdx.x;
  const int l = tid & 63, w = tid >> 6;       // w 0..15
  const int lrow = l & 15, lk = l >> 4;
  const int wm = w >> 2, wn = w & 3;          // 4 x 4 wave grid

  const int nwg = gridDim.x * gridDim.y;
  int lin = blockIdx.y * gridDim.x + blockIdx.x;
  lin = (lin & 7) * (nwg >> 3) + (lin >> 3);
  const int m0 = (lin / gridDim.x) * 256, n0 = (lin % gridDim.x) * (64 * NBU);

  // staging (waves 0-7): thread -> (unit-row tid>>3, phys slot tid&7);
  // src col = (slot ^ row&7)*8
  const bool stager = (tid < 512);
  const int srow = tid >> 3;
  const int scol = ((tid & 7) ^ (srow & 7)) << 3;
  const f16_t* gP[4 + NBU];
#pragma unroll
  for (int u = 0; u < 4; ++u) gP[u] = A + (size_t)(m0 + u * 64 + srow) * lda + scol;
#pragma unroll
  for (int u = 0; u < NBU; ++u) gP[4 + u] = Bm + (size_t)(n0 + u * 64 + srow) * ldb + scol;

  auto stageAll = [&](int buf, int k0) {
#pragma unroll
    for (int u = 0; u < 4 + NBU; ++u)
      gload16(gP[u] + k0, &lds[buf][u * 4096 + tid * 8]);
  };
  auto rdA = [&](int buf, int mf, int ks) -> f16x8 {
    const int row = wm * 64 + mf * 16 + lrow;             // 0..255
    const int slot = ((ks << 2) | lk) ^ (row & 7);
    return *reinterpret_cast<const f16x8*>(&lds[buf][row * 64 + slot * 8]);
  };
  auto rdB = [&](int buf, int nf, int ks) -> f16x8 {
    const int row = wn * (16 * NBU) + nf * 16 + lrow;     // 0..64*NBU-1
    const int slot = ((ks << 2) | lk) ^ (row & 7);
    return *reinterpret_cast<const f16x8*>(&lds[buf][16384 + row * 64 + slot * 8]);
  };

  f32x4 acc[4][NBU] = {};
  const int nkt = K >> 6;

  if (stager) {
    stageAll(0, 0);
    stageAll(1, nkt > 1 ? 64 : 0);
  }
  if constexpr (NBU == 3) { asm volatile("s_waitcnt vmcnt(7)" ::: "memory"); }
  else                    { asm volatile("s_waitcnt vmcnt(6)" ::: "memory"); }
  SCHED0();
  SBAR(); SCHED0();

  f16x8 aA[4][2], bB[NBU][2];
  for (int kt = 0; kt < nkt; ++kt) {
    const int b = kt & 1;
    const int kn2 = (kt + 2 < nkt ? kt + 2 : nkt - 1) << 6;

    // phase 1: read all frags of tile t, MFMA mf 0..1
#pragma unroll
    for (int mf = 0; mf < 4; ++mf) { aA[mf][0] = rdA(b, mf, 0); aA[mf][1] = rdA(b, mf, 1); }
#pragma unroll
    for (int nf = 0; nf < NBU; ++nf) { bB[nf][0] = rdB(b, nf, 0); bB[nf][1] = rdB(b, nf, 1); }
    __builtin_amdgcn_s_setprio(1);
#pragma unroll
    for (int mf = 0; mf < 2; ++mf)
#pragma unroll
      for (int nf = 0; nf < NBU; ++nf)
#pragma unroll
        for (int ks = 0; ks < 2; ++ks)
          acc[mf][nf] = MFMA16F(aA[mf][ks], bB[nf][ks], acc[mf][nf]);
    __builtin_amdgcn_s_setprio(0);
    LGKM0(); SCHED0();       // all my ds_reads of buf b complete
    SBAR(); SCHED0();        // ... on every wave -> safe to overwrite buf b

    // phase 2: stage tile t+2 over dead buf b; wait tile t+1; MFMA mf 2..3
    if (stager) stageAll(b, kn2);
    if constexpr (NBU == 3) { asm volatile("s_waitcnt vmcnt(7)" ::: "memory"); }
    else                    { asm volatile("s_waitcnt vmcnt(6)" ::: "memory"); }
    SCHED0();
    __builtin_amdgcn_s_setprio(1);
#pragma unroll
    for (int mf = 2; mf < 4; ++mf)
#pragma unroll
      for (int nf = 0; nf < NBU; ++nf)
#pragma unroll
        for (int ks = 0; ks < 2; ++ks)
          acc[mf][nf] = MFMA16F(aA[mf][ks], bB[nf][ks], acc[mf][nf]);
    __builtin_amdgcn_s_setprio(0);
    SBAR(); SCHED0();        // all waves past vmcnt -> t+1 resident for next reads
  }

  // C-write: row = m0 + wm*64 + mf*16 + lk*4 + rg ; col = n0 + wn*16*NBU + nf*16 + lrow
#pragma unroll
  for (int mf = 0; mf < 4; ++mf) {
    const int row = m0 + wm * 64 + mf * 16 + lk * 4;
#pragma unroll
    for (int nf = 0; nf < NBU; ++nf) {
      const int col = n0 + wn * (16 * NBU) + nf * 16 + lrow;
#pragma unroll
      for (int rg = 0; rg < 4; ++rg)
        C[(size_t)(row + rg) * N + col] = (OutT)acc[mf][nf][rg];
    }
  }
  (void)M;
}

// ---------------------------------------------------------------------------
// QKV epilogue.  qkv raw = [4096][3072] f16 (q | k | v).  RMS-norm(q,k) +
// partial RoPE in fp32; q gets gain*(1/sqrt(128))*log2(e) folded in; all
// outputs plain f16 [.][128]; v += ve_embed.
// ---------------------------------------------------------------------------
__global__ __launch_bounds__(256) void k_qkv_epi(
    const f16_t* __restrict__ qkv, const float* __restrict__ ve,
    const float* __restrict__ qgain,
    const float* __restrict__ ctab, const float* __restrict__ stab,
    f16_t* __restrict__ qn, f16_t* __restrict__ kn, f16_t* __restrict__ vn)
{
  const int blk = blockIdx.x;           // b*2048 + t
  const int b = blk >> 11, t = blk & 2047;
  const int w = threadIdx.x >> 6, l = threadIdx.x & 63;
  const int i32 = l & 31;
  const float c = ctab[t * 32 + i32], s = stab[t * 32 + i32];
  const float EPS = 1.1920929e-07f;
  constexpr float SCALE_L2E = 0.088388347648318447f * 1.4426950408889634f;

  // Q: wave w handles heads w, w+4, w+8, w+12
#pragma unroll
  for (int it = 0; it < 4; ++it) {
    const int h = w + it * 4;
    const f16_t* row = qkv + (size_t)blk * 3072 + h * 128;
    float x0 = (float)row[l], x1 = (float)row[l + 64];
    float ss = x0 * x0 + x1 * x1;
#pragma unroll
    for (int off = 32; off; off >>= 1) ss += __shfl_xor(ss, off);
    const float rn = rsqrtf(ss * (1.0f / 128.0f) + EPS);
    x0 *= rn; x1 *= rn;
    const float p = __shfl_xor(x0, 32);
    float xr = (l < 32) ? (x0 * c - p * s) : (p * s + x0 * c);
    const float g = qgain[h] * SCALE_L2E;
    xr *= g; x1 *= g;
    f16_t* orow = qn + (((size_t)(b * 16 + h)) * 2048 + t) * 128;
    orow[l] = (f16_t)xr;
    orow[l + 64] = (f16_t)x1;
  }
  // K: wave w -> kv head w
  {
    const f16_t* row = qkv + (size_t)blk * 3072 + 2048 + w * 128;
    float x0 = (float)row[l], x1 = (float)row[l + 64];
    float ss = x0 * x0 + x1 * x1;
#pragma unroll
    for (int off = 32; off; off >>= 1) ss += __shfl_xor(ss, off);
    const float rn = rsqrtf(ss * (1.0f / 128.0f) + EPS);
    x0 *= rn; x1 *= rn;
    const float p = __shfl_xor(x0, 32);
    const float xr = (l < 32) ? (x0 * c - p * s) : (p * s + x0 * c);
    f16_t* orow = kn + (((size_t)(b * 4 + w)) * 2048 + t) * 128;
    orow[l] = (f16_t)xr;
    orow[l + 64] = (f16_t)x1;
  }
  // V: wave w -> kv head w ; v = vraw + ve
  {
    const f16_t* row = qkv + (size_t)blk * 3072 + 2560 + w * 128;
    const float* verow = ve + (size_t)blk * 512 + w * 128;
    f16_t* orow = vn + (((size_t)(b * 4 + w)) * 2048 + t) * 128;
    orow[l] = (f16_t)((float)row[l] + verow[l]);
    orow[l + 64] = (f16_t)((float)row[l + 64] + verow[l + 64]);
  }
}

// ---------------------------------------------------------------------------
// Causal GQA flash attention, fp16 single-precision.  QBLK=64 (4 waves x 16
// q-rows), KVBLK=64, longest-qt-first.  LDS: lsK [64][136] padded (2-way
// reads), lsV^T [128][72] XOR-swizzled, lsP per-wave [16][72].  45KB -> 3
// blocks/CU.  2 barriers/tile.  K+V reg-prefetched one tile ahead.
// Softmax in log2 domain (scale folded into q), defer-max THR=8.
// ---------------------------------------------------------------------------
__global__ __launch_bounds__(256, 3) void k_attn(
    const f16_t* __restrict__ qn, const f16_t* __restrict__ kn,
    const f16_t* __restrict__ vn, f16_t* __restrict__ y)
{
  __shared__ __align__(16) f16_t lsK[64 * 136];      // 17408 B
  __shared__ __align__(16) f16_t lsV[128 * 72];      // 18432 B
  __shared__ __align__(16) f16_t lsPb[4][16 * 72];   //  9216 B
  const int qt = 31 - (int)blockIdx.y;  // longest first
  const int bh = blockIdx.x;            // 0..31
  const int b = bh >> 4, h = bh & 15, kvh = h >> 2;
  const int tid = threadIdx.x, w = tid >> 6, l = tid & 63;
  const int lrow = l & 15, lk = l >> 4;
  const int qbase = qt * 64 + w * 16;
  constexpr float NEG = -1e30f;
  f16_t* lsP = lsPb[w];

  // Q fragments (A-frag: row = lane&15, k = lk*8+j)
  const f16_t* qp = qn + ((size_t)(b * 16 + h) * 2048) * 128;
  f16x8 aQ[4];
#pragma unroll
  for (int kf = 0; kf < 4; ++kf)
    aQ[kf] = *reinterpret_cast<const f16x8*>(
        qp + (size_t)(qbase + lrow) * 128 + kf * 32 + lk * 8);

  const f16_t* kp = kn + ((size_t)(b * 4 + kvh) * 2048) * 128;
  const f16_t* vp = vn + ((size_t)(b * 4 + kvh) * 2048) * 128;

  f32x4 o[8] = {};
  float mst[4], lst[4];
#pragma unroll
  for (int rg = 0; rg < 4; ++rg) { mst[rg] = NEG; lst[rg] = 0.f; }

  // K/V register prefetch (tile t0): chunk cch = tid + it*256,
  // row = cch>>4 (0..63), slot = cch&15.
  f16x8 kreg[4], vreg[4];
  auto loadKV = [&](int t0) {
#pragma unroll
    for (int it = 0; it < 4; ++it) {
      const int cch = tid + it * 256;
      const size_t goff = (size_t)(t0 + (cch >> 4)) * 128 + (cch & 15) * 8;
      kreg[it] = *reinterpret_cast<const f16x8*>(kp + goff);
      vreg[it] = *reinterpret_cast<const f16x8*>(vp + goff);
    }
  };
  loadKV(0);

  const int ntiles = qt + 1;
  for (int tt = 0; tt < ntiles; ++tt) {
    __syncthreads();  // prior tile's K/V LDS reads done before restage
    // stage K [64][136] + V^T [128][72] (col' = kv ^ ((dg&7)<<3)) from regs
#pragma unroll
    for (int it = 0; it < 4; ++it) {
      const int cch = tid + it * 256;
      const int r = cch >> 4, dg = cch & 15;
      *reinterpret_cast<f16x8*>(&lsK[r * 136 + dg * 8]) = kreg[it];
      const int colb = r ^ ((dg & 7) << 3);
#pragma unroll
      for (int j = 0; j < 8; ++j) lsV[(dg * 8 + j) * 72 + colb] = vreg[it][j];
    }
    // prefetch next tile's K/V (in flight across S + softmax + PV)
    if (tt + 1 < ntiles) loadKV((tt + 1) * 64);
    __syncthreads();  // staged data visible

    // S = Q K^T  (16 q-rows x 64 kv)
    f32x4 sacc[4] = {};
#pragma unroll
    for (int cf = 0; cf < 4; ++cf) {
      const int krow = cf * 16 + lrow;
#pragma unroll
      for (int kf = 0; kf < 4; ++kf) {
        const f16x8 bK = *reinterpret_cast<const f16x8*>(
            &lsK[krow * 136 + kf * 32 + lk * 8]);
        sacc[cf] = MFMA16F(aQ[kf], bK, sacc[cf]);
      }
    }

    // online softmax, log2 domain; mask only on diagonal tile
    if (tt == qt) {
#pragma unroll
      for (int rg = 0; rg < 4; ++rg) {
        const int qi = w * 16 + lk * 4 + rg;  // within-tile row
#pragma unroll
        for (int cf = 0; cf < 4; ++cf)
          if (cf * 16 + lrow > qi) sacc[cf][rg] = NEG;
      }
    }
    float pmax[4];
#pragma unroll
    for (int rg = 0; rg < 4; ++rg) {
      float mx = fmaxf(fmaxf(sacc[0][rg], sacc[1][rg]),
                       fmaxf(sacc[2][rg], sacc[3][rg]));
      mx = fmaxf(mx, __shfl_xor(mx, 1));
      mx = fmaxf(mx, __shfl_xor(mx, 2));
      mx = fmaxf(mx, __shfl_xor(mx, 4));
      mx = fmaxf(mx, __shfl_xor(mx, 8));
      pmax[rg] = mx;
    }
    const bool grow = (pmax[0] > mst[0] + 8.f) | (pmax[1] > mst[1] + 8.f) |
                      (pmax[2] > mst[2] + 8.f) | (pmax[3] > mst[3] + 8.f);
    if (__any(grow)) {
#pragma unroll
      for (int rg = 0; rg < 4; ++rg) {
        const float mnew = fmaxf(mst[rg], pmax[rg]);
        const float alpha = exp2f(mst[rg] - mnew);
        mst[rg] = mnew;
        lst[rg] *= alpha;
#pragma unroll
        for (int df = 0; df < 8; ++df) o[df][rg] *= alpha;
      }
    }
#pragma unroll
    for (int rg = 0; rg < 4; ++rg) {
      float rsum = 0.f;
#pragma unroll
      for (int cf = 0; cf < 4; ++cf) {
        const float p = exp2f(sacc[cf][rg] - mst[rg]);
        sacc[cf][rg] = p;
        rsum += p;
      }
      rsum += __shfl_xor(rsum, 1);
      rsum += __shfl_xor(rsum, 2);
      rsum += __shfl_xor(rsum, 4);
      rsum += __shfl_xor(rsum, 8);
      lst[rg] += rsum;
    }

    // P -> per-wave LDS (A-frag layout [16][72]); same-wave write->read
#pragma unroll
    for (int cf = 0; cf < 4; ++cf)
#pragma unroll
      for (int rg = 0; rg < 4; ++rg)
        lsP[(lk * 4 + rg) * 72 + cf * 16 + lrow] = (f16_t)sacc[cf][rg];
    // PV
#pragma unroll
    for (int k2 = 0; k2 < 2; ++k2) {
      const f16x8 aP = *reinterpret_cast<const f16x8*>(
          &lsP[lrow * 72 + k2 * 32 + lk * 8]);
#pragma unroll
      for (int df = 0; df < 8; ++df) {
        const int row = df * 16 + lrow;
        const int colb = (k2 * 32 + lk * 8) ^ (((row >> 3) & 7) << 3);
        const f16x8 bV = *reinterpret_cast<const f16x8*>(&lsV[row * 72 + colb]);
        o[df] = MFMA16F(aP, bV, o[df]);
      }
    }
  }

  // normalize + write y [b][t][h*128+d]
#pragma unroll
  for (int rg = 0; rg < 4; ++rg) {
    const float inv = 1.0f / lst[rg];
    const int qi = qbase + lk * 4 + rg;
    const size_t rowoff = ((size_t)(b * 2048 + qi)) * 2048 + h * 128;
#pragma unroll
    for (int df = 0; df < 8; ++df)
      y[rowoff + df * 16 + lrow] = (f16_t)(o[df][rg] * inv);
  }
}

// ---------------------------------------------------------------------------
extern "C" void kernel_launch(void* const* d_in, const int* in_sizes, int n_in,
                              void* d_out, int out_size, void* d_ws, size_t ws_size,
                              hipStream_t stream) {
  const float* x  = (const float*)d_in[0];
  const float* ve = (const float*)d_in[1];
  const float* Wq = (const float*)d_in[2];
  const float* Wk = (const float*)d_in[3];
  const float* Wv = (const float*)d_in[4];
  const float* Wp = (const float*)d_in[5];
  const float* qg = (const float*)d_in[6];
  float* out = (float*)d_out;

  char* ws = (char*)d_ws;
  size_t off = 0;
  auto alloc = [&](size_t bytes) -> char* {
    char* p = ws + off;
    off += (bytes + 255) & ~(size_t)255;
    return p;
  };

  f16_t* xf    = (f16_t*)alloc((size_t)4096 * 2048 * 2);   // later qn
  f16_t* wqkvf = (f16_t*)alloc((size_t)3072 * 2048 * 2);   // rows Wq|Wk|Wv
  f16_t* wpf   = (f16_t*)alloc((size_t)2048 * 2048 * 2);
  f16_t* qkvf  = (f16_t*)alloc((size_t)4096 * 3072 * 2);   // GEMM out; later yb
  f16_t* kn    = (f16_t*)alloc((size_t)2 * 4 * 2048 * 128 * 2);
  f16_t* vn    = (f16_t*)alloc((size_t)2 * 4 * 2048 * 128 * 2);
  float* ctab  = (float*)alloc((size_t)2048 * 32 * 4);
  float* stab  = (float*)alloc((size_t)2048 * 32 * 4);
  f16_t* qn    = xf;      // xf dead after QKV GEMM (16MB = 16MB)
  f16_t* yb    = qkvf;    // qkvf dead after epilogue (y 16.8MB <= 25.2MB)
  (void)ws_size; (void)in_sizes; (void)n_in; (void)out_size;

  k_cast_f16<<<1024, 256, 0, stream>>>(x, xf, (long)4096 * 2048);
  k_cast_wqkv<<<1536, 256, 0, stream>>>(Wq, Wk, Wv, wqkvf);
  k_cast_f16<<<1024, 256, 0, stream>>>(Wp, wpf, (long)2048 * 2048);
  k_rope_tab<<<256, 256, 0, stream>>>(ctab, stab);

  // qkvf = x·[Wq|Wk|Wv]^T  (M=4096 N=3072 K=2048; 256x192 tiles, grid 16x16)
  k_gemmQ<3, f16_t><<<dim3(16, 16), 1024, 0, stream>>>(
      xf, wqkvf, qkvf, 4096, 3072, 2048, 2048, 2048);

  k_qkv_epi<<<4096, 256, 0, stream>>>(qkvf, ve, qg, ctab, stab, qn, kn, vn);

  k_attn<<<dim3(32, 32), 256, 0, stream>>>(qn, kn, vn, yb);

  // out = y · Wp^T  (M=4096 N=2048 K=2048; 256x128 tiles, grid 16x16)
  k_gemmQ<2, float><<<dim3(16, 16), 1024, 0, stream>>>(
      yb, wpf, out, 4096, 2048, 2048, 2048, 2048);
}

// Round 12
// 215.165 us; speedup vs baseline: 1.7580x; 1.0042x over previous
//
#include <hip/hip_runtime.h>
#include <hip/hip_bf16.h>
#include <cstdint>
#include <cstddef>

// ---------------------------------------------------------------------------
// CausalSelfAttention fused block, MI355X/gfx950.  Round 12:
//  - V pre-transposed once globally (k_vtrans, ~4us) -> attn stages lsV^T
//    with 4 vectorized b128 stores instead of 32 scalar stores + ~100 VALU
//    per thread per tile (R11's conflict + VALU hotspot).
//  - everything else unchanged from R11 (fp16 chain, 2-phase GEMMs).
// B=2 T=2048 D=2048 NH=16 NKV=4 HD=128 ROPE=64.
// ---------------------------------------------------------------------------

typedef _Float16 f16_t;
typedef f16_t f16x8 __attribute__((ext_vector_type(8)));
typedef float f32x4 __attribute__((ext_vector_type(4)));

#define MFMA16F(a, b, c) __builtin_amdgcn_mfma_f32_16x16x32_f16((a), (b), (c), 0, 0, 0)
#define SBAR()   __builtin_amdgcn_s_barrier()
#define SCHED0() __builtin_amdgcn_sched_barrier(0)
#define LGKM0()  asm volatile("s_waitcnt lgkmcnt(0)" ::: "memory")

__device__ __forceinline__ void gload16(const f16_t* g, f16_t* l) {
  auto lds_ptr = reinterpret_cast<__attribute__((address_space(3))) unsigned int*>(
      reinterpret_cast<uintptr_t>(l));
  auto g_ptr = reinterpret_cast<const __attribute__((address_space(1))) unsigned int*>(
      reinterpret_cast<uintptr_t>(g));
  __builtin_amdgcn_global_load_lds(g_ptr, lds_ptr, 16, 0, 0);
}

// ---------------------------------------------------------------------------
// fp32 -> fp16 cast, vectorized
// ---------------------------------------------------------------------------
__global__ void k_cast_f16(const float* __restrict__ in, f16_t* __restrict__ o, long n) {
  long i = ((long)blockIdx.x * blockDim.x + threadIdx.x) * 4;
  const long step = (long)gridDim.x * blockDim.x * 4;
  for (; i < n; i += step) {
    const float4 v = *reinterpret_cast<const float4*>(in + i);
    f16_t r[4] = {(f16_t)v.x, (f16_t)v.y, (f16_t)v.z, (f16_t)v.w};
    *reinterpret_cast<uint64_t*>(o + i) = *reinterpret_cast<const uint64_t*>(r);
  }
}

// ---------------------------------------------------------------------------
// merged W cast: rows 0-2047 Wq, 2048-2559 Wk, 2560-3071 Wv -> wf [3072][2048]
// ---------------------------------------------------------------------------
__global__ void k_cast_wqkv(const float* __restrict__ Wq, const float* __restrict__ Wk,
                            const float* __restrict__ Wv, f16_t* __restrict__ wf) {
  long i = ((long)blockIdx.x * blockDim.x + threadIdx.x) * 4;
  const long step = (long)gridDim.x * blockDim.x * 4;
  for (; i < (long)3072 * 2048; i += step) {
    const long row = i >> 11, col = i & 2047;
    const float* src = (row < 2048) ? (Wq + (size_t)row * 2048)
                     : (row < 2560) ? (Wk + (size_t)(row - 2048) * 2048)
                                    : (Wv + (size_t)(row - 2560) * 2048);
    const float4 v = *reinterpret_cast<const float4*>(src + col);
    f16_t r[4] = {(f16_t)v.x, (f16_t)v.y, (f16_t)v.z, (f16_t)v.w};
    *reinterpret_cast<uint64_t*>(wf + row * 2048 + col) = *reinterpret_cast<const uint64_t*>(r);
  }
}

// ---------------------------------------------------------------------------
// RoPE cos/sin table: [T=2048][32]
// ---------------------------------------------------------------------------
__global__ void k_rope_tab(float* __restrict__ ctab, float* __restrict__ stab) {
  const int idx = blockIdx.x * blockDim.x + threadIdx.x;
  if (idx >= 2048 * 32) return;
  const int t = idx >> 5, i = idx & 31;
  const float freq = exp2f(-(float)i * 0.2076205059304601f);  // 10000^(-i/64)
  const float f = (float)t * freq;
  ctab[idx] = cosf(f);
  stab[idx] = sinf(f);
}

// ---------------------------------------------------------------------------
// V transpose: vn [bk][2048 t][128 d] -> vt [bk][128 d][2048 t].
// grid (32 tchunk, 8 bk), 256 thr.  64t x 128d tile via LDS.
// ---------------------------------------------------------------------------
__global__ __launch_bounds__(256) void k_vtrans(
    const f16_t* __restrict__ vn, f16_t* __restrict__ vt)
{
  __shared__ __align__(16) f16_t lsT[64 * 136];
  const int t0 = blockIdx.x * 64;
  const int bk = blockIdx.y;
  const f16_t* src = vn + ((size_t)bk * 2048 + t0) * 128;
  f16_t* dst = vt + (size_t)bk * 128 * 2048;
  const int tid = threadIdx.x;
#pragma unroll
  for (int it = 0; it < 4; ++it) {
    const int cch = tid + it * 256;
    const int r = cch >> 4, c = cch & 15;
    *reinterpret_cast<f16x8*>(&lsT[r * 136 + c * 8]) =
        *reinterpret_cast<const f16x8*>(src + (size_t)r * 128 + c * 8);
  }
  __syncthreads();
#pragma unroll
  for (int it = 0; it < 4; ++it) {
    const int u = tid + it * 256;
    const int d = u >> 3, c8 = u & 7;
    f16_t vals[8];
#pragma unroll
    for (int j = 0; j < 8; ++j) vals[j] = lsT[(c8 * 8 + j) * 136 + d];
    *reinterpret_cast<f16x8*>(dst + (size_t)d * 2048 + t0 + c8 * 8) =
        *reinterpret_cast<const f16x8*>(vals);
  }
}

// ---------------------------------------------------------------------------
// 256 x (64*NBU) NT GEMM, fp16 in, OutT out (R10/R11 proven).
// 1024 threads = 16 waves (4M x 4N); BK=64; 2-phase counted-vmcnt.
// ---------------------------------------------------------------------------
template <int NBU, typename OutT>
__global__ __launch_bounds__(1024, 1) void k_gemmQ(
    const f16_t* __restrict__ A, const f16_t* __restrict__ Bm,
    OutT* __restrict__ C, int M, int N, int K, int lda, int ldb)
{
  __shared__ __align__(16) f16_t lds[2][(4 + NBU) * 4096];
  const int tid = threadIdx.x;
  const int l = tid & 63, w = tid >> 6;       // w 0..15
  const int lrow = l & 15, lk = l >> 4;
  const int wm = w >> 2, wn = w & 3;          // 4 x 4 wave grid

  const int nwg = gridDim.x * gridDim.y;
  int lin = blockIdx.y * gridDim.x + blockIdx.x;
  lin = (lin & 7) * (nwg >> 3) + (lin >> 3);
  const int m0 = (lin / gridDim.x) * 256, n0 = (lin % gridDim.x) * (64 * NBU);

  const bool stager = (tid < 512);
  const int srow = tid >> 3;
  const int scol = ((tid & 7) ^ (srow & 7)) << 3;
  const f16_t* gP[4 + NBU];
#pragma unroll
  for (int u = 0; u < 4; ++u) gP[u] = A + (size_t)(m0 + u * 64 + srow) * lda + scol;
#pragma unroll
  for (int u = 0; u < NBU; ++u) gP[4 + u] = Bm + (size_t)(n0 + u * 64 + srow) * ldb + scol;

  auto stageAll = [&](int buf, int k0) {
#pragma unroll
    for (int u = 0; u < 4 + NBU; ++u)
      gload16(gP[u] + k0, &lds[buf][u * 4096 + tid * 8]);
  };
  auto rdA = [&](int buf, int mf, int ks) -> f16x8 {
    const int row = wm * 64 + mf * 16 + lrow;             // 0..255
    const int slot = ((ks << 2) | lk) ^ (row & 7);
    return *reinterpret_cast<const f16x8*>(&lds[buf][row * 64 + slot * 8]);
  };
  auto rdB = [&](int buf, int nf, int ks) -> f16x8 {
    const int row = wn * (16 * NBU) + nf * 16 + lrow;     // 0..64*NBU-1
    const int slot = ((ks << 2) | lk) ^ (row & 7);
    return *reinterpret_cast<const f16x8*>(&lds[buf][16384 + row * 64 + slot * 8]);
  };

  f32x4 acc[4][NBU] = {};
  const int nkt = K >> 6;

  if (stager) {
    stageAll(0, 0);
    stageAll(1, nkt > 1 ? 64 : 0);
  }
  if constexpr (NBU == 3) { asm volatile("s_waitcnt vmcnt(7)" ::: "memory"); }
  else                    { asm volatile("s_waitcnt vmcnt(6)" ::: "memory"); }
  SCHED0();
  SBAR(); SCHED0();

  f16x8 aA[4][2], bB[NBU][2];
  for (int kt = 0; kt < nkt; ++kt) {
    const int b = kt & 1;
    const int kn2 = (kt + 2 < nkt ? kt + 2 : nkt - 1) << 6;

    // phase 1: read all frags of tile t, MFMA mf 0..1
#pragma unroll
    for (int mf = 0; mf < 4; ++mf) { aA[mf][0] = rdA(b, mf, 0); aA[mf][1] = rdA(b, mf, 1); }
#pragma unroll
    for (int nf = 0; nf < NBU; ++nf) { bB[nf][0] = rdB(b, nf, 0); bB[nf][1] = rdB(b, nf, 1); }
    __builtin_amdgcn_s_setprio(1);
#pragma unroll
    for (int mf = 0; mf < 2; ++mf)
#pragma unroll
      for (int nf = 0; nf < NBU; ++nf)
#pragma unroll
        for (int ks = 0; ks < 2; ++ks)
          acc[mf][nf] = MFMA16F(aA[mf][ks], bB[nf][ks], acc[mf][nf]);
    __builtin_amdgcn_s_setprio(0);
    LGKM0(); SCHED0();
    SBAR(); SCHED0();

    // phase 2: stage tile t+2 over dead buf b; wait tile t+1; MFMA mf 2..3
    if (stager) stageAll(b, kn2);
    if constexpr (NBU == 3) { asm volatile("s_waitcnt vmcnt(7)" ::: "memory"); }
    else                    { asm volatile("s_waitcnt vmcnt(6)" ::: "memory"); }
    SCHED0();
    __builtin_amdgcn_s_setprio(1);
#pragma unroll
    for (int mf = 2; mf < 4; ++mf)
#pragma unroll
      for (int nf = 0; nf < NBU; ++nf)
#pragma unroll
        for (int ks = 0; ks < 2; ++ks)
          acc[mf][nf] = MFMA16F(aA[mf][ks], bB[nf][ks], acc[mf][nf]);
    __builtin_amdgcn_s_setprio(0);
    SBAR(); SCHED0();
  }

  // C-write
#pragma unroll
  for (int mf = 0; mf < 4; ++mf) {
    const int row = m0 + wm * 64 + mf * 16 + lk * 4;
#pragma unroll
    for (int nf = 0; nf < NBU; ++nf) {
      const int col = n0 + wn * (16 * NBU) + nf * 16 + lrow;
#pragma unroll
      for (int rg = 0; rg < 4; ++rg)
        C[(size_t)(row + rg) * N + col] = (OutT)acc[mf][nf][rg];
    }
  }
  (void)M;
}

// ---------------------------------------------------------------------------
// QKV epilogue (unchanged from R11).
// ---------------------------------------------------------------------------
__global__ __launch_bounds__(256) void k_qkv_epi(
    const f16_t* __restrict__ qkv, const float* __restrict__ ve,
    const float* __restrict__ qgain,
    const float* __restrict__ ctab, const float* __restrict__ stab,
    f16_t* __restrict__ qn, f16_t* __restrict__ kn, f16_t* __restrict__ vn)
{
  const int blk = blockIdx.x;           // b*2048 + t
  const int b = blk >> 11, t = blk & 2047;
  const int w = threadIdx.x >> 6, l = threadIdx.x & 63;
  const int i32 = l & 31;
  const float c = ctab[t * 32 + i32], s = stab[t * 32 + i32];
  const float EPS = 1.1920929e-07f;
  constexpr float SCALE_L2E = 0.088388347648318447f * 1.4426950408889634f;

#pragma unroll
  for (int it = 0; it < 4; ++it) {
    const int h = w + it * 4;
    const f16_t* row = qkv + (size_t)blk * 3072 + h * 128;
    float x0 = (float)row[l], x1 = (float)row[l + 64];
    float ss = x0 * x0 + x1 * x1;
#pragma unroll
    for (int off = 32; off; off >>= 1) ss += __shfl_xor(ss, off);
    const float rn = rsqrtf(ss * (1.0f / 128.0f) + EPS);
    x0 *= rn; x1 *= rn;
    const float p = __shfl_xor(x0, 32);
    float xr = (l < 32) ? (x0 * c - p * s) : (p * s + x0 * c);
    const float g = qgain[h] * SCALE_L2E;
    xr *= g; x1 *= g;
    f16_t* orow = qn + (((size_t)(b * 16 + h)) * 2048 + t) * 128;
    orow[l] = (f16_t)xr;
    orow[l + 64] = (f16_t)x1;
  }
  {
    const f16_t* row = qkv + (size_t)blk * 3072 + 2048 + w * 128;
    float x0 = (float)row[l], x1 = (float)row[l + 64];
    float ss = x0 * x0 + x1 * x1;
#pragma unroll
    for (int off = 32; off; off >>= 1) ss += __shfl_xor(ss, off);
    const float rn = rsqrtf(ss * (1.0f / 128.0f) + EPS);
    x0 *= rn; x1 *= rn;
    const float p = __shfl_xor(x0, 32);
    const float xr = (l < 32) ? (x0 * c - p * s) : (p * s + x0 * c);
    f16_t* orow = kn + (((size_t)(b * 4 + w)) * 2048 + t) * 128;
    orow[l] = (f16_t)xr;
    orow[l + 64] = (f16_t)x1;
  }
  {
    const f16_t* row = qkv + (size_t)blk * 3072 + 2560 + w * 128;
    const float* verow = ve + (size_t)blk * 512 + w * 128;
    f16_t* orow = vn + (((size_t)(b * 4 + w)) * 2048 + t) * 128;
    orow[l] = (f16_t)((float)row[l] + verow[l]);
    orow[l + 64] = (f16_t)((float)row[l + 64] + verow[l + 64]);
  }
}

// ---------------------------------------------------------------------------
// Causal GQA flash attention, fp16.  QBLK=64 (4 waves x 16 q-rows), KVBLK=64,
// longest-qt-first.  LDS: lsK [64][136] padded, lsV^T [128][72] XOR-swizzled
// (staged VECTORIZED from pre-transposed vt), lsP per-wave [16][72].
// 45KB -> 3 blocks/CU.  2 barriers/tile.  K+V reg-prefetched one tile ahead.
// ---------------------------------------------------------------------------
__global__ __launch_bounds__(256, 3) void k_attn(
    const f16_t* __restrict__ qn, const f16_t* __restrict__ kn,
    const f16_t* __restrict__ vt, f16_t* __restrict__ y)
{
  __shared__ __align__(16) f16_t lsK[64 * 136];      // 17408 B
  __shared__ __align__(16) f16_t lsV[128 * 72];      // 18432 B
  __shared__ __align__(16) f16_t lsPb[4][16 * 72];   //  9216 B
  const int qt = 31 - (int)blockIdx.y;  // longest first
  const int bh = blockIdx.x;            // 0..31
  const int b = bh >> 4, h = bh & 15, kvh = h >> 2;
  const int tid = threadIdx.x, w = tid >> 6, l = tid & 63;
  const int lrow = l & 15, lk = l >> 4;
  const int qbase = qt * 64 + w * 16;
  constexpr float NEG = -1e30f;
  f16_t* lsP = lsPb[w];

  // Q fragments (A-frag: row = lane&15, k = lk*8+j)
  const f16_t* qp = qn + ((size_t)(b * 16 + h) * 2048) * 128;
  f16x8 aQ[4];
#pragma unroll
  for (int kf = 0; kf < 4; ++kf)
    aQ[kf] = *reinterpret_cast<const f16x8*>(
        qp + (size_t)(qbase + lrow) * 128 + kf * 32 + lk * 8);

  const f16_t* kp = kn + ((size_t)(b * 4 + kvh) * 2048) * 128;
  const f16_t* vtp = vt + (size_t)(b * 4 + kvh) * 128 * 2048;

  f32x4 o[8] = {};
  float mst[4], lst[4];
#pragma unroll
  for (int rg = 0; rg < 4; ++rg) { mst[rg] = NEG; lst[rg] = 0.f; }

  // K prefetch: chunk cch = tid + it*256: row = cch>>4 (0..63), slot = cch&15
  // V^T prefetch: d = cch>>3 (0..127), c8 = cch&7 -> vt row d, 8 t's
  f16x8 kreg[4], vreg[4];
  auto loadKV = [&](int t0) {
#pragma unroll
    for (int it = 0; it < 4; ++it) {
      const int cch = tid + it * 256;
      kreg[it] = *reinterpret_cast<const f16x8*>(
          kp + (size_t)(t0 + (cch >> 4)) * 128 + (cch & 15) * 8);
      vreg[it] = *reinterpret_cast<const f16x8*>(
          vtp + (size_t)(cch >> 3) * 2048 + t0 + (cch & 7) * 8);
    }
  };
  loadKV(0);

  const int ntiles = qt + 1;
  for (int tt = 0; tt < ntiles; ++tt) {
    __syncthreads();  // prior tile's K/V LDS reads done before restage
    // stage K [64][136] + V^T [128][72] (col8' = c8 ^ ((d>>3)&7)), all b128
#pragma unroll
    for (int it = 0; it < 4; ++it) {
      const int cch = tid + it * 256;
      const int r = cch >> 4, dg = cch & 15;
      *reinterpret_cast<f16x8*>(&lsK[r * 136 + dg * 8]) = kreg[it];
      const int d = cch >> 3, c8 = cch & 7;
      *reinterpret_cast<f16x8*>(&lsV[d * 72 + ((c8 ^ ((d >> 3) & 7)) << 3)]) = vreg[it];
    }
    // prefetch next tile's K/V (in flight across S + softmax + PV)
    if (tt + 1 < ntiles) loadKV((tt + 1) * 64);
    __syncthreads();  // staged data visible

    // S = Q K^T  (16 q-rows x 64 kv)
    f32x4 sacc[4] = {};
#pragma unroll
    for (int cf = 0; cf < 4; ++cf) {
      const int krow = cf * 16 + lrow;
#pragma unroll
      for (int kf = 0; kf < 4; ++kf) {
        const f16x8 bK = *reinterpret_cast<const f16x8*>(
            &lsK[krow * 136 + kf * 32 + lk * 8]);
        sacc[cf] = MFMA16F(aQ[kf], bK, sacc[cf]);
      }
    }

    // online softmax, log2 domain; mask only on diagonal tile
    if (tt == qt) {
#pragma unroll
      for (int rg = 0; rg < 4; ++rg) {
        const int qi = w * 16 + lk * 4 + rg;  // within-tile row
#pragma unroll
        for (int cf = 0; cf < 4; ++cf)
          if (cf * 16 + lrow > qi) sacc[cf][rg] = NEG;
      }
    }
    float pmax[4];
#pragma unroll
    for (int rg = 0; rg < 4; ++rg) {
      float mx = fmaxf(fmaxf(sacc[0][rg], sacc[1][rg]),
                       fmaxf(sacc[2][rg], sacc[3][rg]));
      mx = fmaxf(mx, __shfl_xor(mx, 1));
      mx = fmaxf(mx, __shfl_xor(mx, 2));
      mx = fmaxf(mx, __shfl_xor(mx, 4));
      mx = fmaxf(mx, __shfl_xor(mx, 8));
      pmax[rg] = mx;
    }
    const bool grow = (pmax[0] > mst[0] + 8.f) | (pmax[1] > mst[1] + 8.f) |
                      (pmax[2] > mst[2] + 8.f) | (pmax[3] > mst[3] + 8.f);
    if (__any(grow)) {
#pragma unroll
      for (int rg = 0; rg < 4; ++rg) {
        const float mnew = fmaxf(mst[rg], pmax[rg]);
        const float alpha = exp2f(mst[rg] - mnew);
        mst[rg] = mnew;
        lst[rg] *= alpha;
#pragma unroll
        for (int df = 0; df < 8; ++df) o[df][rg] *= alpha;
      }
    }
#pragma unroll
    for (int rg = 0; rg < 4; ++rg) {
      float rsum = 0.f;
#pragma unroll
      for (int cf = 0; cf < 4; ++cf) {
        const float p = exp2f(sacc[cf][rg] - mst[rg]);
        sacc[cf][rg] = p;
        rsum += p;
      }
      rsum += __shfl_xor(rsum, 1);
      rsum += __shfl_xor(rsum, 2);
      rsum += __shfl_xor(rsum, 4);
      rsum += __shfl_xor(rsum, 8);
      lst[rg] += rsum;
    }

    // P -> per-wave LDS (A-frag layout [16][72]); same-wave write->read
#pragma unroll
    for (int cf = 0; cf < 4; ++cf)
#pragma unroll
      for (int rg = 0; rg < 4; ++rg)
        lsP[(lk * 4 + rg) * 72 + cf * 16 + lrow] = (f16_t)sacc[cf][rg];
    // PV
#pragma unroll
    for (int k2 = 0; k2 < 2; ++k2) {
      const f16x8 aP = *reinterpret_cast<const f16x8*>(
          &lsP[lrow * 72 + k2 * 32 + lk * 8]);
#pragma unroll
      for (int df = 0; df < 8; ++df) {
        const int row = df * 16 + lrow;
        const int colb = (k2 * 32 + lk * 8) ^ (((row >> 3) & 7) << 3);
        const f16x8 bV = *reinterpret_cast<const f16x8*>(&lsV[row * 72 + colb]);
        o[df] = MFMA16F(aP, bV, o[df]);
      }
    }
  }

  // normalize + write y [b][t][h*128+d]
#pragma unroll
  for (int rg = 0; rg < 4; ++rg) {
    const float inv = 1.0f / lst[rg];
    const int qi = qbase + lk * 4 + rg;
    const size_t rowoff = ((size_t)(b * 2048 + qi)) * 2048 + h * 128;
#pragma unroll
    for (int df = 0; df < 8; ++df)
      y[rowoff + df * 16 + lrow] = (f16_t)(o[df][rg] * inv);
  }
}

// ---------------------------------------------------------------------------
extern "C" void kernel_launch(void* const* d_in, const int* in_sizes, int n_in,
                              void* d_out, int out_size, void* d_ws, size_t ws_size,
                              hipStream_t stream) {
  const float* x  = (const float*)d_in[0];
  const float* ve = (const float*)d_in[1];
  const float* Wq = (const float*)d_in[2];
  const float* Wk = (const float*)d_in[3];
  const float* Wv = (const float*)d_in[4];
  const float* Wp = (const float*)d_in[5];
  const float* qg = (const float*)d_in[6];
  float* out = (float*)d_out;

  char* ws = (char*)d_ws;
  size_t off = 0;
  auto alloc = [&](size_t bytes) -> char* {
    char* p = ws + off;
    off += (bytes + 255) & ~(size_t)255;
    return p;
  };

  f16_t* xf    = (f16_t*)alloc((size_t)4096 * 2048 * 2);   // later qn
  f16_t* wqkvf = (f16_t*)alloc((size_t)3072 * 2048 * 2);   // rows Wq|Wk|Wv
  f16_t* wpf   = (f16_t*)alloc((size_t)2048 * 2048 * 2);
  f16_t* qkvf  = (f16_t*)alloc((size_t)4096 * 3072 * 2);   // GEMM out; later yb
  f16_t* kn    = (f16_t*)alloc((size_t)2 * 4 * 2048 * 128 * 2);
  f16_t* vn    = (f16_t*)alloc((size_t)2 * 4 * 2048 * 128 * 2);
  f16_t* vt    = (f16_t*)alloc((size_t)2 * 4 * 128 * 2048 * 2);
  float* ctab  = (float*)alloc((size_t)2048 * 32 * 4);
  float* stab  = (float*)alloc((size_t)2048 * 32 * 4);
  f16_t* qn    = xf;      // xf dead after QKV GEMM
  f16_t* yb    = qkvf;    // qkvf dead after epilogue
  (void)ws_size; (void)in_sizes; (void)n_in; (void)out_size;

  k_cast_f16<<<1024, 256, 0, stream>>>(x, xf, (long)4096 * 2048);
  k_cast_wqkv<<<1536, 256, 0, stream>>>(Wq, Wk, Wv, wqkvf);
  k_cast_f16<<<1024, 256, 0, stream>>>(Wp, wpf, (long)2048 * 2048);
  k_rope_tab<<<256, 256, 0, stream>>>(ctab, stab);

  // qkvf = x·[Wq|Wk|Wv]^T  (M=4096 N=3072 K=2048; 256x192 tiles, grid 16x16)
  k_gemmQ<3, f16_t><<<dim3(16, 16), 1024, 0, stream>>>(
      xf, wqkvf, qkvf, 4096, 3072, 2048, 2048, 2048);

  k_qkv_epi<<<4096, 256, 0, stream>>>(qkvf, ve, qg, ctab, stab, qn, kn, vn);

  k_vtrans<<<dim3(32, 8), 256, 0, stream>>>(vn, vt);

  k_attn<<<dim3(32, 32), 256, 0, stream>>>(qn, kn, vt, yb);

  // out = y · Wp^T  (M=4096 N=2048 K=2048; 256x128 tiles, grid 16x16)
  k_gemmQ<2, float><<<dim3(16, 16), 1024, 0, stream>>>(
      yb, wpf, out, 4096, 2048, 2048, 2048, 2048);
}